// Round 1
// baseline (3465.161 us; speedup 1.0000x reference)
//
#include <hip/hip_runtime.h>
#include <math.h>

// CrystalGraphConvolution — MI355X round 1 (correctness + structure baseline)
//
// Factorization: merged@K = x[src]@K_top + x[dst]@K_mid + edge@K_bot.
//   - C  = edge@K_bot (s,g interleaved), step-invariant -> computed once/launch.
//   - PQ = per-node projections (Ps,Pg | Qs,Qg interleaved), recomputed per step.
//   - edge_apply: gather PQ rows, add C + bias, sigmoid*softplus, atomicAdd to acc.
//   - acc lives in d_out: acc = x; atomics add agg; act_k applies softplus in place.

#define NN 50000
#define NE 800000
#define AD 128
#define ED 64
#define NSTEPS 3

__device__ __forceinline__ float sigmoid_f(float x) {
    float e = __expf(-fabsf(x));
    return (x >= 0.f) ? 1.f / (1.f + e) : e / (1.f + e);
}
__device__ __forceinline__ float softplus_f(float x) {
    return fmaxf(x, 0.f) + log1pf(__expf(-fabsf(x)));
}

// ---- node projections: PQ[node][512] = [ (Ps,Pg) x128 | (Qs,Qg) x128 ] ----
__global__ void __launch_bounds__(128) node_mm(
    const float* __restrict__ x, const float* __restrict__ Ks,
    const float* __restrict__ Kg, float* __restrict__ PQ)
{
    __shared__ float xs[8][AD];
    const int t = threadIdx.x;
    const int row0 = blockIdx.x * 8;
#pragma unroll
    for (int r = 0; r < 8; ++r) xs[r][t] = x[(size_t)(row0 + r) * AD + t];
    __syncthreads();

    float aPs[8] = {}, aQs[8] = {}, aPg[8] = {}, aQg[8] = {};
    for (int k = 0; k < AD; ++k) {
        float ks_s = Ks[k * AD + t];
        float ks_d = Ks[(AD + k) * AD + t];
        float kg_s = Kg[k * AD + t];
        float kg_d = Kg[(AD + k) * AD + t];
#pragma unroll
        for (int r = 0; r < 8; ++r) {
            float xv = xs[r][k];                 // LDS broadcast (free)
            aPs[r] = fmaf(xv, ks_s, aPs[r]);
            aQs[r] = fmaf(xv, ks_d, aQs[r]);
            aPg[r] = fmaf(xv, kg_s, aPg[r]);
            aQg[r] = fmaf(xv, kg_d, aQg[r]);
        }
    }
#pragma unroll
    for (int r = 0; r < 8; ++r) {
        float* o = PQ + (size_t)(row0 + r) * 512;
        *(float2*)&o[2 * t]       = make_float2(aPs[r], aPg[r]);
        *(float2*)&o[256 + 2 * t] = make_float2(aQs[r], aQg[r]);
    }
}

// ---- C = edge_feat @ K_bot, interleaved (s,g): C[e][2n],C[e][2n+1] ----
__global__ void __launch_bounds__(256) edge_c(
    const float* __restrict__ ef, const float* __restrict__ Ks,
    const float* __restrict__ Kg, float* __restrict__ C)
{
    __shared__ float KB[ED][2 * AD];  // 64 KB, [k][2n]=Ks_bot,[2n+1]=Kg_bot
    __shared__ float es[64][ED];      // 16 KB edge-feature tile
    const int t = threadIdx.x;
    for (int i = t; i < ED * AD; i += 256) {
        int k = i >> 7, n = i & 127;
        KB[k][2 * n]     = Ks[(2 * AD + k) * AD + n];
        KB[k][2 * n + 1] = Kg[(2 * AD + k) * AD + n];
    }
    const size_t e0 = (size_t)blockIdx.x * 64;
    for (int i = t; i < 64 * ED; i += 256) ((float*)es)[i] = ef[e0 * ED + i];
    __syncthreads();

    const int le = t >> 7, n = t & 127;
    for (int base = le * 8; base < 64; base += 16) {
        float accS[8] = {}, accG[8] = {};
        for (int k4 = 0; k4 < ED / 4; ++k4) {
            float2 kv0 = *(const float2*)&KB[4 * k4 + 0][2 * n];  // b64, conflict-free
            float2 kv1 = *(const float2*)&KB[4 * k4 + 1][2 * n];
            float2 kv2 = *(const float2*)&KB[4 * k4 + 2][2 * n];
            float2 kv3 = *(const float2*)&KB[4 * k4 + 3][2 * n];
#pragma unroll
            for (int r = 0; r < 8; ++r) {
                float4 ev = *(const float4*)&es[base + r][4 * k4];  // b128 broadcast
                accS[r] = fmaf(ev.x, kv0.x, accS[r]);
                accG[r] = fmaf(ev.x, kv0.y, accG[r]);
                accS[r] = fmaf(ev.y, kv1.x, accS[r]);
                accG[r] = fmaf(ev.y, kv1.y, accG[r]);
                accS[r] = fmaf(ev.z, kv2.x, accS[r]);
                accG[r] = fmaf(ev.z, kv2.y, accG[r]);
                accS[r] = fmaf(ev.w, kv3.x, accS[r]);
                accG[r] = fmaf(ev.w, kv3.y, accG[r]);
            }
        }
#pragma unroll
        for (int r = 0; r < 8; ++r) {
            float* c = C + (e0 + base + r) * 256;
            *(float2*)&c[2 * n] = make_float2(accS[r], accG[r]);
        }
    }
}

// ---- per-edge message + atomic segment-sum (C precomputed) ----
__global__ void __launch_bounds__(256) edge_apply(
    const float* __restrict__ C, const float* __restrict__ PQ,
    const int* __restrict__ pidx, const float* __restrict__ bs,
    const float* __restrict__ bg, float* __restrict__ acc)
{
    const int t = threadIdx.x;
    const int le = t >> 7, n = t & 127;
    const size_t e = (size_t)blockIdx.x * 2 + le;
    const int src = pidx[2 * e], dst = pidx[2 * e + 1];
    float2 cv = *(const float2*)&C[e * 256 + 2 * n];
    float2 pv = *(const float2*)&PQ[(size_t)src * 512 + 2 * n];
    float2 qv = *(const float2*)&PQ[(size_t)dst * 512 + 256 + 2 * n];
    float s = cv.x + pv.x + qv.x + bs[n];
    float g = cv.y + pv.y + qv.y + bg[n];
    float msg = sigmoid_f(s) * softplus_f(g);
    atomicAdd(&acc[(size_t)src * AD + n], msg);
}

// ---- fallback: compute C in-loop (no C buffer), then apply ----
__global__ void __launch_bounds__(256) edge_fused(
    const float* __restrict__ ef, const float* __restrict__ Ks,
    const float* __restrict__ Kg, const float* __restrict__ PQ,
    const int* __restrict__ pidx, const float* __restrict__ bs,
    const float* __restrict__ bg, float* __restrict__ acc)
{
    __shared__ float KB[ED][2 * AD];
    __shared__ float es[64][ED];
    const int t = threadIdx.x;
    for (int i = t; i < ED * AD; i += 256) {
        int k = i >> 7, n = i & 127;
        KB[k][2 * n]     = Ks[(2 * AD + k) * AD + n];
        KB[k][2 * n + 1] = Kg[(2 * AD + k) * AD + n];
    }
    const size_t e0 = (size_t)blockIdx.x * 64;
    for (int i = t; i < 64 * ED; i += 256) ((float*)es)[i] = ef[e0 * ED + i];
    __syncthreads();

    const int le = t >> 7, n = t & 127;
    const float bsn = bs[n], bgn = bg[n];
    for (int base = le * 8; base < 64; base += 16) {
        float accS[8] = {}, accG[8] = {};
        for (int k4 = 0; k4 < ED / 4; ++k4) {
            float2 kv0 = *(const float2*)&KB[4 * k4 + 0][2 * n];
            float2 kv1 = *(const float2*)&KB[4 * k4 + 1][2 * n];
            float2 kv2 = *(const float2*)&KB[4 * k4 + 2][2 * n];
            float2 kv3 = *(const float2*)&KB[4 * k4 + 3][2 * n];
#pragma unroll
            for (int r = 0; r < 8; ++r) {
                float4 ev = *(const float4*)&es[base + r][4 * k4];
                accS[r] = fmaf(ev.x, kv0.x, accS[r]);
                accG[r] = fmaf(ev.x, kv0.y, accG[r]);
                accS[r] = fmaf(ev.y, kv1.x, accS[r]);
                accG[r] = fmaf(ev.y, kv1.y, accG[r]);
                accS[r] = fmaf(ev.z, kv2.x, accS[r]);
                accG[r] = fmaf(ev.z, kv2.y, accG[r]);
                accS[r] = fmaf(ev.w, kv3.x, accS[r]);
                accG[r] = fmaf(ev.w, kv3.y, accG[r]);
            }
        }
#pragma unroll
        for (int r = 0; r < 8; ++r) {
            size_t e = e0 + base + r;
            int src = pidx[2 * e], dst = pidx[2 * e + 1];
            float2 pv = *(const float2*)&PQ[(size_t)src * 512 + 2 * n];
            float2 qv = *(const float2*)&PQ[(size_t)dst * 512 + 256 + 2 * n];
            float s = accS[r] + pv.x + qv.x + bsn;
            float g = accG[r] + pv.y + qv.y + bgn;
            atomicAdd(&acc[(size_t)src * AD + n], sigmoid_f(s) * softplus_f(g));
        }
    }
}

// ---- in-place softplus on the accumulator ----
__global__ void __launch_bounds__(256) act_k(float* __restrict__ acc)
{
    size_t i = ((size_t)blockIdx.x * 256 + threadIdx.x) * 4;
    float4 v = *(float4*)&acc[i];
    v.x = softplus_f(v.x);
    v.y = softplus_f(v.y);
    v.z = softplus_f(v.z);
    v.w = softplus_f(v.w);
    *(float4*)&acc[i] = v;
}

extern "C" void kernel_launch(void* const* d_in, const int* in_sizes, int n_in,
                              void* d_out, int out_size, void* d_ws, size_t ws_size,
                              hipStream_t stream)
{
    const float* atom = (const float*)d_in[0];
    const float* ef   = (const float*)d_in[1];
    // d_in[2] = state_attrs (unused by the reference computation)
    const float* Ks   = (const float*)d_in[3];
    const float* bs   = (const float*)d_in[4];
    const float* Kg   = (const float*)d_in[5];
    const float* bg   = (const float*)d_in[6];
    const int*   pidx = (const int*)d_in[7];
    // d_in[8], d_in[9] graph indices: unused

    float* acc = (float*)d_out;                     // doubles as x / x+agg buffer
    float* PQ  = (float*)d_ws;                      // NN x 512 f32 = 102.4 MB
    const size_t PQ_BYTES = (size_t)NN * 512 * 4;
    float* C = (float*)((char*)d_ws + PQ_BYTES);    // NE x 256 f32 = 819.2 MB
    const size_t C_BYTES = (size_t)NE * 256 * 4;
    const bool useC = ws_size >= PQ_BYTES + C_BYTES;

    // acc = atom_features
    hipMemcpyAsync(acc, atom, (size_t)NN * AD * sizeof(float),
                   hipMemcpyDeviceToDevice, stream);

    if (useC) edge_c<<<NE / 64, 256, 0, stream>>>(ef, Ks, Kg, C);

    for (int s = 0; s < NSTEPS; ++s) {
        node_mm<<<NN / 8, 128, 0, stream>>>(acc, Ks, Kg, PQ);
        if (useC)
            edge_apply<<<NE / 2, 256, 0, stream>>>(C, PQ, pidx, bs, bg, acc);
        else
            edge_fused<<<NE / 64, 256, 0, stream>>>(ef, Ks, Kg, PQ, pidx, bs, bg, acc);
        act_k<<<(NN * AD) / 1024, 256, 0, stream>>>(acc);
    }
}

// Round 2
// 2445.842 us; speedup vs baseline: 1.4168x; 1.4168x over previous
//
#include <hip/hip_runtime.h>
#include <hip/hip_bf16.h>
#include <math.h>

// CrystalGraphConvolution — MI355X round 2
// Tier A (ws >= 471 MB): one-time { counting-sort edges by src; C = ef@K_bot in bf16,
//   stored in SORTED edge order }. Per step: node projections (bf16 PQ), then a
//   sorted apply kernel: linear C stream + Q gather + per-run P broadcast +
//   one atomicAdd per src-run (atomics 400 MB -> ~28 MB).
// Tier B fallback (= round-1 path, known-good): f32 PQ + fused per-step C.

#define NN 50000
#define NE 800000
#define AD 128
#define ED 64
#define NSTEPS 3

__device__ __forceinline__ float sigmoid_f(float x) {
    float e = __expf(-fabsf(x));
    return (x >= 0.f) ? 1.f / (1.f + e) : e / (1.f + e);
}
__device__ __forceinline__ float softplus_f(float x) {
    return fmaxf(x, 0.f) + log1pf(__expf(-fabsf(x)));
}
__device__ __forceinline__ unsigned pack_bf2(float s, float g) {
    __hip_bfloat16 hs = __float2bfloat16(s), hg = __float2bfloat16(g);
    unsigned short us = *(unsigned short*)&hs, ug = *(unsigned short*)&hg;
    return (unsigned)us | ((unsigned)ug << 16);
}
__device__ __forceinline__ float unp_lo(unsigned v) { return __uint_as_float(v << 16); }
__device__ __forceinline__ float unp_hi(unsigned v) { return __uint_as_float(v & 0xffff0000u); }

// ================= Tier A kernels =================

// node projections -> bf16 packed PQ32[node][256]: [0,128)=(Ps,Pg), [128,256)=(Qs,Qg)
__global__ void __launch_bounds__(128) node_mm_b16(
    const float* __restrict__ x, const float* __restrict__ Ks,
    const float* __restrict__ Kg, unsigned* __restrict__ PQ32)
{
    __shared__ float xs[8][AD];
    const int t = threadIdx.x;
    const int row0 = blockIdx.x * 8;
#pragma unroll
    for (int r = 0; r < 8; ++r) xs[r][t] = x[(size_t)(row0 + r) * AD + t];
    __syncthreads();

    float aPs[8] = {}, aQs[8] = {}, aPg[8] = {}, aQg[8] = {};
    for (int k = 0; k < AD; ++k) {
        float ks_s = Ks[k * AD + t];
        float ks_d = Ks[(AD + k) * AD + t];
        float kg_s = Kg[k * AD + t];
        float kg_d = Kg[(AD + k) * AD + t];
#pragma unroll
        for (int r = 0; r < 8; ++r) {
            float xv = xs[r][k];
            aPs[r] = fmaf(xv, ks_s, aPs[r]);
            aQs[r] = fmaf(xv, ks_d, aQs[r]);
            aPg[r] = fmaf(xv, kg_s, aPg[r]);
            aQg[r] = fmaf(xv, kg_d, aQg[r]);
        }
    }
#pragma unroll
    for (int r = 0; r < 8; ++r) {
        unsigned* o = PQ32 + (size_t)(row0 + r) * 256;
        o[t]       = pack_bf2(aPs[r], aPg[r]);
        o[128 + t] = pack_bf2(aQs[r], aQg[r]);
    }
}

// histogram of src
__global__ void __launch_bounds__(256) hist_k(const int* __restrict__ pidx,
                                              unsigned* __restrict__ cnt)
{
    int e = blockIdx.x * 256 + threadIdx.x;
    atomicAdd(&cnt[pidx[2 * e]], 1u);
}

// exclusive prefix sum over NN bins (single block)
__global__ void __launch_bounds__(1024) scan_k(const unsigned* __restrict__ cnt,
                                               unsigned* __restrict__ cur)
{
    __shared__ unsigned tmp[1024];
    __shared__ unsigned s_carry;
    const int t = threadIdx.x;
    if (t == 0) s_carry = 0;
    __syncthreads();
    for (int base = 0; base < NN; base += 1024) {
        unsigned v = (base + t < NN) ? cnt[base + t] : 0u;
        unsigned c0 = s_carry;
        tmp[t] = v;
        __syncthreads();
        for (int off = 1; off < 1024; off <<= 1) {
            unsigned a = (t >= off) ? tmp[t - off] : 0u;
            __syncthreads();
            tmp[t] += a;
            __syncthreads();
        }
        if (base + t < NN) cur[base + t] = c0 + tmp[t] - v;  // exclusive
        if (t == 1023) s_carry = c0 + tmp[1023];
        __syncthreads();
    }
}

// scatter: inv[e]=sorted pos; ssrc/sdst = src/dst in sorted order
__global__ void __launch_bounds__(256) scatter_k(
    const int* __restrict__ pidx, unsigned* __restrict__ cur,
    unsigned* __restrict__ inv, int* __restrict__ ssrc, int* __restrict__ sdst)
{
    int e = blockIdx.x * 256 + threadIdx.x;
    int s = pidx[2 * e], d = pidx[2 * e + 1];
    unsigned pos = atomicAdd(&cur[s], 1u);
    inv[e] = pos;
    ssrc[pos] = s;
    sdst[pos] = d;
}

// C = ef @ K_bot (bf16 packed (s,g)), written at SORTED position inv[e]
__global__ void __launch_bounds__(256) edge_c_b16(
    const float* __restrict__ ef, const float* __restrict__ Ks,
    const float* __restrict__ Kg, const unsigned* __restrict__ inv,
    unsigned* __restrict__ C32)
{
    __shared__ float KB[ED][2 * AD];  // 64 KB
    __shared__ float es[64][ED];      // 16 KB
    const int t = threadIdx.x;
    for (int i = t; i < ED * AD; i += 256) {
        int k = i >> 7, n = i & 127;
        KB[k][2 * n]     = Ks[(2 * AD + k) * AD + n];
        KB[k][2 * n + 1] = Kg[(2 * AD + k) * AD + n];
    }
    const size_t e0 = (size_t)blockIdx.x * 64;
    for (int i = t; i < 64 * ED; i += 256) ((float*)es)[i] = ef[e0 * ED + i];
    __syncthreads();

    const int le = t >> 7, n = t & 127;
    for (int base = le * 8; base < 64; base += 16) {
        float accS[8] = {}, accG[8] = {};
        for (int k4 = 0; k4 < ED / 4; ++k4) {
            float2 kv0 = *(const float2*)&KB[4 * k4 + 0][2 * n];
            float2 kv1 = *(const float2*)&KB[4 * k4 + 1][2 * n];
            float2 kv2 = *(const float2*)&KB[4 * k4 + 2][2 * n];
            float2 kv3 = *(const float2*)&KB[4 * k4 + 3][2 * n];
#pragma unroll
            for (int r = 0; r < 8; ++r) {
                float4 ev = *(const float4*)&es[base + r][4 * k4];
                accS[r] = fmaf(ev.x, kv0.x, accS[r]);
                accG[r] = fmaf(ev.x, kv0.y, accG[r]);
                accS[r] = fmaf(ev.y, kv1.x, accS[r]);
                accG[r] = fmaf(ev.y, kv1.y, accG[r]);
                accS[r] = fmaf(ev.z, kv2.x, accS[r]);
                accG[r] = fmaf(ev.z, kv2.y, accG[r]);
                accS[r] = fmaf(ev.w, kv3.x, accS[r]);
                accG[r] = fmaf(ev.w, kv3.y, accG[r]);
            }
        }
#pragma unroll
        for (int r = 0; r < 8; ++r) {
            size_t pos = inv[e0 + base + r];
            C32[pos * 128 + n] = pack_bf2(accS[r], accG[r]);
        }
    }
}

// sorted apply: linear C stream, Q gather, per-run P broadcast, one atomic per run
__global__ void __launch_bounds__(128) edge_apply_sorted(
    const unsigned* __restrict__ C32, const unsigned* __restrict__ PQ32,
    const int* __restrict__ ssrc, const int* __restrict__ sdst,
    const float* __restrict__ bs, const float* __restrict__ bg,
    float* __restrict__ acc)
{
    __shared__ int s_src[128], s_dst[128];
    const int t = threadIdx.x;
    const size_t p0 = (size_t)blockIdx.x * 128;
    s_src[t] = ssrc[p0 + t];
    s_dst[t] = sdst[p0 + t];
    __syncthreads();

    const float bsn = bs[t], bgn = bg[t];
    int cur = s_src[0];
    unsigned pv = PQ32[(size_t)cur * 256 + t];
    // depth-2 prefetch of the streamed C row and gathered Q row
    unsigned cA = C32[(p0 + 0) * 128 + t];
    unsigned qA = PQ32[(size_t)s_dst[0] * 256 + 128 + t];
    unsigned cB = C32[(p0 + 1) * 128 + t];
    unsigned qB = PQ32[(size_t)s_dst[1] * 256 + 128 + t];
    float accv = 0.f;

    for (int i = 0; i < 128; ++i) {
        unsigned cc = cA, qq = qA;
        cA = cB; qA = qB;
        if (i + 2 < 128) {
            cB = C32[(p0 + i + 2) * 128 + t];
            qB = PQ32[(size_t)s_dst[i + 2] * 256 + 128 + t];
        }
        int src = s_src[i];
        if (src != cur) {                       // wave-uniform branch
            atomicAdd(&acc[(size_t)cur * AD + t], accv);
            accv = 0.f;
            cur = src;
            pv = PQ32[(size_t)cur * 256 + t];
        }
        float s = unp_lo(cc) + unp_lo(pv) + unp_lo(qq) + bsn;
        float g = unp_hi(cc) + unp_hi(pv) + unp_hi(qq) + bgn;
        accv += sigmoid_f(s) * softplus_f(g);
    }
    atomicAdd(&acc[(size_t)cur * AD + t], accv);
}

// ================= Tier B fallback (round-1, known good) =================

__global__ void __launch_bounds__(128) node_mm_f32(
    const float* __restrict__ x, const float* __restrict__ Ks,
    const float* __restrict__ Kg, float* __restrict__ PQ)
{
    __shared__ float xs[8][AD];
    const int t = threadIdx.x;
    const int row0 = blockIdx.x * 8;
#pragma unroll
    for (int r = 0; r < 8; ++r) xs[r][t] = x[(size_t)(row0 + r) * AD + t];
    __syncthreads();

    float aPs[8] = {}, aQs[8] = {}, aPg[8] = {}, aQg[8] = {};
    for (int k = 0; k < AD; ++k) {
        float ks_s = Ks[k * AD + t];
        float ks_d = Ks[(AD + k) * AD + t];
        float kg_s = Kg[k * AD + t];
        float kg_d = Kg[(AD + k) * AD + t];
#pragma unroll
        for (int r = 0; r < 8; ++r) {
            float xv = xs[r][k];
            aPs[r] = fmaf(xv, ks_s, aPs[r]);
            aQs[r] = fmaf(xv, ks_d, aQs[r]);
            aPg[r] = fmaf(xv, kg_s, aPg[r]);
            aQg[r] = fmaf(xv, kg_d, aQg[r]);
        }
    }
#pragma unroll
    for (int r = 0; r < 8; ++r) {
        float* o = PQ + (size_t)(row0 + r) * 512;
        *(float2*)&o[2 * t]       = make_float2(aPs[r], aPg[r]);
        *(float2*)&o[256 + 2 * t] = make_float2(aQs[r], aQg[r]);
    }
}

__global__ void __launch_bounds__(256) edge_fused(
    const float* __restrict__ ef, const float* __restrict__ Ks,
    const float* __restrict__ Kg, const float* __restrict__ PQ,
    const int* __restrict__ pidx, const float* __restrict__ bs,
    const float* __restrict__ bg, float* __restrict__ acc)
{
    __shared__ float KB[ED][2 * AD];
    __shared__ float es[64][ED];
    const int t = threadIdx.x;
    for (int i = t; i < ED * AD; i += 256) {
        int k = i >> 7, n = i & 127;
        KB[k][2 * n]     = Ks[(2 * AD + k) * AD + n];
        KB[k][2 * n + 1] = Kg[(2 * AD + k) * AD + n];
    }
    const size_t e0 = (size_t)blockIdx.x * 64;
    for (int i = t; i < 64 * ED; i += 256) ((float*)es)[i] = ef[e0 * ED + i];
    __syncthreads();

    const int le = t >> 7, n = t & 127;
    const float bsn = bs[n], bgn = bg[n];
    for (int base = le * 8; base < 64; base += 16) {
        float accS[8] = {}, accG[8] = {};
        for (int k4 = 0; k4 < ED / 4; ++k4) {
            float2 kv0 = *(const float2*)&KB[4 * k4 + 0][2 * n];
            float2 kv1 = *(const float2*)&KB[4 * k4 + 1][2 * n];
            float2 kv2 = *(const float2*)&KB[4 * k4 + 2][2 * n];
            float2 kv3 = *(const float2*)&KB[4 * k4 + 3][2 * n];
#pragma unroll
            for (int r = 0; r < 8; ++r) {
                float4 ev = *(const float4*)&es[base + r][4 * k4];
                accS[r] = fmaf(ev.x, kv0.x, accS[r]);
                accG[r] = fmaf(ev.x, kv0.y, accG[r]);
                accS[r] = fmaf(ev.y, kv1.x, accS[r]);
                accG[r] = fmaf(ev.y, kv1.y, accG[r]);
                accS[r] = fmaf(ev.z, kv2.x, accS[r]);
                accG[r] = fmaf(ev.z, kv2.y, accG[r]);
                accS[r] = fmaf(ev.w, kv3.x, accS[r]);
                accG[r] = fmaf(ev.w, kv3.y, accG[r]);
            }
        }
#pragma unroll
        for (int r = 0; r < 8; ++r) {
            size_t e = e0 + base + r;
            int src = pidx[2 * e], dst = pidx[2 * e + 1];
            float2 pv = *(const float2*)&PQ[(size_t)src * 512 + 2 * n];
            float2 qv = *(const float2*)&PQ[(size_t)dst * 512 + 256 + 2 * n];
            float s = accS[r] + pv.x + qv.x + bsn;
            float g = accG[r] + pv.y + qv.y + bgn;
            atomicAdd(&acc[(size_t)src * AD + n], sigmoid_f(s) * softplus_f(g));
        }
    }
}

__global__ void __launch_bounds__(256) act_k(float* __restrict__ acc)
{
    size_t i = ((size_t)blockIdx.x * 256 + threadIdx.x) * 4;
    float4 v = *(float4*)&acc[i];
    v.x = softplus_f(v.x);
    v.y = softplus_f(v.y);
    v.z = softplus_f(v.z);
    v.w = softplus_f(v.w);
    *(float4*)&acc[i] = v;
}

// ================= launch =================

extern "C" void kernel_launch(void* const* d_in, const int* in_sizes, int n_in,
                              void* d_out, int out_size, void* d_ws, size_t ws_size,
                              hipStream_t stream)
{
    const float* atom = (const float*)d_in[0];
    const float* ef   = (const float*)d_in[1];
    const float* Ks   = (const float*)d_in[3];
    const float* bs   = (const float*)d_in[4];
    const float* Kg   = (const float*)d_in[5];
    const float* bg   = (const float*)d_in[6];
    const int*   pidx = (const int*)d_in[7];

    float* acc = (float*)d_out;

    // Tier A workspace layout
    char* w = (char*)d_ws;
    const size_t PQ_B   = (size_t)NN * 256 * 4;   //  51.2 MB
    const size_t C_B    = (size_t)NE * 128 * 4;   // 409.6 MB
    const size_t CNT_B  = (size_t)NN * 4;         //   0.2 MB
    const size_t IDX_B  = (size_t)NE * 4;         //   3.2 MB
    unsigned* PQ32 = (unsigned*)w;                 w += PQ_B;
    unsigned* C32  = (unsigned*)w;                 w += C_B;
    unsigned* cnt  = (unsigned*)w;                 w += CNT_B;
    unsigned* curp = (unsigned*)w;                 w += CNT_B;
    unsigned* inv  = (unsigned*)w;                 w += IDX_B;
    int*      ssrc = (int*)w;                      w += IDX_B;
    int*      sdst = (int*)w;                      w += IDX_B;
    const size_t TOTAL_A = PQ_B + C_B + 2 * CNT_B + 3 * IDX_B;  // ~470.8 MB

    hipMemcpyAsync(acc, atom, (size_t)NN * AD * sizeof(float),
                   hipMemcpyDeviceToDevice, stream);

    if (ws_size >= TOTAL_A) {
        // one-time: sort by src, then C in sorted order
        hipMemsetAsync(cnt, 0, CNT_B, stream);
        hist_k<<<NE / 256, 256, 0, stream>>>(pidx, cnt);
        scan_k<<<1, 1024, 0, stream>>>(cnt, curp);
        scatter_k<<<NE / 256, 256, 0, stream>>>(pidx, curp, inv, ssrc, sdst);
        edge_c_b16<<<NE / 64, 256, 0, stream>>>(ef, Ks, Kg, inv, C32);

        for (int s = 0; s < NSTEPS; ++s) {
            node_mm_b16<<<NN / 8, 128, 0, stream>>>(acc, Ks, Kg, PQ32);
            edge_apply_sorted<<<NE / 128, 128, 0, stream>>>(C32, PQ32, ssrc, sdst,
                                                            bs, bg, acc);
            act_k<<<(NN * AD) / 1024, 256, 0, stream>>>(acc);
        }
    } else {
        // Tier B: round-1 path (f32 PQ, per-step fused C)
        float* PQ = (float*)d_ws;  // NN*512*4 = 102.4 MB
        for (int s = 0; s < NSTEPS; ++s) {
            node_mm_f32<<<NN / 8, 128, 0, stream>>>(acc, Ks, Kg, PQ);
            edge_fused<<<NE / 64, 256, 0, stream>>>(ef, Ks, Kg, PQ, pidx, bs, bg, acc);
            act_k<<<(NN * AD) / 1024, 256, 0, stream>>>(acc);
        }
    }
}

// Round 3
// 1276.452 us; speedup vs baseline: 2.7147x; 1.9161x over previous
//
#include <hip/hip_runtime.h>
#include <hip/hip_bf16.h>
#include <math.h>

// CrystalGraphConvolution — MI355X round 3
// Tier A: sort edges by src (one-time); C = ef@K_bot via MFMA bf16 with hi/lo
//   split (f32-grade accuracy), stored bf16-packed in sorted order; per step:
//   node projections (VALU f32 -> bf16 PQ), sorted apply (linear C stream,
//   Q gather, per-run P broadcast + prefetched P, one atomic per run), softplus.
// Tier B fallback: round-1 path.

#define NN 50000
#define NE 800000
#define AD 128
#define ED 64
#define NSTEPS 3
#define NTILES (NE / 64)   // 12500

typedef __attribute__((ext_vector_type(8))) __bf16 bf16x8;
typedef __attribute__((ext_vector_type(4))) float  f32x4;

__device__ __forceinline__ float sigmoid_fast(float x) {
    float e = __expf(-fabsf(x));
    float r = __builtin_amdgcn_rcpf(1.f + e);
    return (x >= 0.f) ? r : 1.f - r;
}
__device__ __forceinline__ float softplus_fast(float x) {
    return fmaxf(x, 0.f) + __logf(1.f + __expf(-fabsf(x)));
}
__device__ __forceinline__ float msg_f(float s, float g) {
    return sigmoid_fast(s) * softplus_fast(g);
}
__device__ __forceinline__ float softplus_f(float x) {  // precise (output path)
    return fmaxf(x, 0.f) + log1pf(__expf(-fabsf(x)));
}
__device__ __forceinline__ unsigned short bf16_rne(float f) {
    unsigned u = __float_as_uint(f);
    unsigned r = u + 0x7fffu + ((u >> 16) & 1u);
    return (unsigned short)(r >> 16);
}
__device__ __forceinline__ unsigned pack_bf2(float s, float g) {
    return (unsigned)bf16_rne(s) | ((unsigned)bf16_rne(g) << 16);
}
__device__ __forceinline__ float unp_lo(unsigned v) { return __uint_as_float(v << 16); }
__device__ __forceinline__ float unp_hi(unsigned v) { return __uint_as_float(v & 0xffff0000u); }

// ================= node projections (bf16 packed PQ) =================
__global__ void __launch_bounds__(128) node_mm_b16(
    const float* __restrict__ x, const float* __restrict__ Ks,
    const float* __restrict__ Kg, unsigned* __restrict__ PQ32)
{
    __shared__ float xs[8][AD];
    const int t = threadIdx.x;
    const int row0 = blockIdx.x * 8;
#pragma unroll
    for (int r = 0; r < 8; ++r) xs[r][t] = x[(size_t)(row0 + r) * AD + t];
    __syncthreads();

    float aPs[8] = {}, aQs[8] = {}, aPg[8] = {}, aQg[8] = {};
    for (int k = 0; k < AD; ++k) {
        float ks_s = Ks[k * AD + t];
        float ks_d = Ks[(AD + k) * AD + t];
        float kg_s = Kg[k * AD + t];
        float kg_d = Kg[(AD + k) * AD + t];
#pragma unroll
        for (int r = 0; r < 8; ++r) {
            float xv = xs[r][k];
            aPs[r] = fmaf(xv, ks_s, aPs[r]);
            aQs[r] = fmaf(xv, ks_d, aQs[r]);
            aPg[r] = fmaf(xv, kg_s, aPg[r]);
            aQg[r] = fmaf(xv, kg_d, aQg[r]);
        }
    }
#pragma unroll
    for (int r = 0; r < 8; ++r) {
        unsigned* o = PQ32 + (size_t)(row0 + r) * 256;
        o[t]       = pack_bf2(aPs[r], aPg[r]);
        o[128 + t] = pack_bf2(aQs[r], aQg[r]);
    }
}

// ================= sort machinery =================
__global__ void __launch_bounds__(256) hist_k(const int* __restrict__ pidx,
                                              unsigned* __restrict__ cnt)
{
    int e = blockIdx.x * 256 + threadIdx.x;
    atomicAdd(&cnt[pidx[2 * e]], 1u);
}

__global__ void __launch_bounds__(1024) scan_k(const unsigned* __restrict__ cnt,
                                               unsigned* __restrict__ cur)
{
    __shared__ unsigned tmp[1024];
    __shared__ unsigned s_carry;
    const int t = threadIdx.x;
    if (t == 0) s_carry = 0;
    __syncthreads();
    for (int base = 0; base < NN; base += 1024) {
        unsigned v = (base + t < NN) ? cnt[base + t] : 0u;
        unsigned c0 = s_carry;
        tmp[t] = v;
        __syncthreads();
        for (int off = 1; off < 1024; off <<= 1) {
            unsigned a = (t >= off) ? tmp[t - off] : 0u;
            __syncthreads();
            tmp[t] += a;
            __syncthreads();
        }
        if (base + t < NN) cur[base + t] = c0 + tmp[t] - v;
        if (t == 1023) s_carry = c0 + tmp[1023];
        __syncthreads();
    }
}

__global__ void __launch_bounds__(256) scatter_k(
    const int* __restrict__ pidx, unsigned* __restrict__ cur,
    unsigned* __restrict__ inv, int* __restrict__ ssrc, int* __restrict__ sdst)
{
    int e = blockIdx.x * 256 + threadIdx.x;
    int s = pidx[2 * e], d = pidx[2 * e + 1];
    unsigned pos = atomicAdd(&cur[s], 1u);
    inv[e] = pos;
    ssrc[pos] = s;
    sdst[pos] = d;
}

// ================= C = ef @ K_bot via MFMA (hi/lo split) =================
// LDS 80 KB: As hi/lo [64 rows][64 k] swizzled; Bt 4 planes (Sh,Sl,Gh,Gl)
// [128 n][64 k] transposed+swizzled. Per wave: 2 S-col-tiles + same-index
// G-col-tiles so (s_n,g_n) land in the same lane for packed stores.
__global__ void __launch_bounds__(256) edge_c_mfma(
    const float* __restrict__ ef, const float* __restrict__ Ks,
    const float* __restrict__ Kg, const unsigned* __restrict__ inv,
    unsigned* __restrict__ C32)
{
    __shared__ short As_h[64 * 64];
    __shared__ short As_l[64 * 64];
    __shared__ short Bt[4][128 * 64];   // 0=Sh 1=Sl 2=Gh 3=Gl
    const int t = threadIdx.x;
    const int w = t >> 6, lane = t & 63;

    // stage B (once per block): read K_bot rows coalesced, write transposed
    for (int i = t; i < 64 * 128; i += 256) {
        int k = i >> 7, n = i & 127;
        float vs = Ks[(size_t)(2 * AD + k) * AD + n];
        float vg = Kg[(size_t)(2 * AD + k) * AD + n];
        int sidx = (n * 64 + k) ^ ((n & 7) << 3);   // short-index swizzle
        unsigned short sh = bf16_rne(vs);
        unsigned short sl = bf16_rne(vs - __uint_as_float((unsigned)sh << 16));
        unsigned short gh = bf16_rne(vg);
        unsigned short gl = bf16_rne(vg - __uint_as_float((unsigned)gh << 16));
        Bt[0][sidx] = (short)sh; Bt[1][sidx] = (short)sl;
        Bt[2][sidx] = (short)gh; Bt[3][sidx] = (short)gl;
    }
    __syncthreads();

    // preload B fragments (per wave): [pair][k-step][hi/lo]
    bf16x8 bS[2][2][2], bG[2][2][2];
#pragma unroll
    for (int p = 0; p < 2; ++p) {
        int col = (2 * w + p) * 16 + (lane & 15);
#pragma unroll
        for (int ki = 0; ki < 2; ++ki) {
            int idx = (col * 64 + ki * 32 + (lane >> 4) * 8) ^ ((col & 7) << 3);
            bS[p][ki][0] = *(const bf16x8*)&Bt[0][idx];
            bS[p][ki][1] = *(const bf16x8*)&Bt[1][idx];
            bG[p][ki][0] = *(const bf16x8*)&Bt[2][idx];
            bG[p][ki][1] = *(const bf16x8*)&Bt[3][idx];
        }
    }

    // A-tile register prefetch: 4 x float4 per thread covers 64x64 f32
    float4 pf0, pf1, pf2, pf3;
    {
        const float4* src = (const float4*)(ef + (size_t)blockIdx.x * 64 * 64);
        if (blockIdx.x < NTILES) {
            pf0 = src[t]; pf1 = src[t + 256]; pf2 = src[t + 512]; pf3 = src[t + 768];
        }
    }

    for (int tile = blockIdx.x; tile < NTILES; tile += gridDim.x) {
        __syncthreads();   // previous tile's MFMA reads of As done
        // convert + write A hi/lo to LDS (swizzled)
        {
            float4 v[4] = {pf0, pf1, pf2, pf3};
#pragma unroll
            for (int ii = 0; ii < 4; ++ii) {
                int i = t + 256 * ii, row = i >> 4, c4 = i & 15;
                float a0 = v[ii].x, a1 = v[ii].y, a2 = v[ii].z, a3 = v[ii].w;
                unsigned short h0 = bf16_rne(a0), h1 = bf16_rne(a1),
                               h2 = bf16_rne(a2), h3 = bf16_rne(a3);
                unsigned short l0 = bf16_rne(a0 - __uint_as_float((unsigned)h0 << 16));
                unsigned short l1 = bf16_rne(a1 - __uint_as_float((unsigned)h1 << 16));
                unsigned short l2 = bf16_rne(a2 - __uint_as_float((unsigned)h2 << 16));
                unsigned short l3 = bf16_rne(a3 - __uint_as_float((unsigned)h3 << 16));
                int sidx = (row * 64 + c4 * 4) ^ ((row & 7) << 3);
                *(short4*)&As_h[sidx] = make_short4((short)h0, (short)h1, (short)h2, (short)h3);
                *(short4*)&As_l[sidx] = make_short4((short)l0, (short)l1, (short)l2, (short)l3);
            }
        }
        // issue next tile's loads (overlap with MFMA below)
        {
            int nxt = tile + gridDim.x;
            if (nxt < NTILES) {
                const float4* src = (const float4*)(ef + (size_t)nxt * 64 * 64);
                pf0 = src[t]; pf1 = src[t + 256]; pf2 = src[t + 512]; pf3 = src[t + 768];
            }
        }
        __syncthreads();

        f32x4 accS[4][2] = {}, accG[4][2] = {};
#pragma unroll
        for (int mt = 0; mt < 4; ++mt) {
#pragma unroll
            for (int ki = 0; ki < 2; ++ki) {
                int row = mt * 16 + (lane & 15);
                int idx = (row * 64 + ki * 32 + (lane >> 4) * 8) ^ ((row & 7) << 3);
                bf16x8 ah = *(const bf16x8*)&As_h[idx];
                bf16x8 al = *(const bf16x8*)&As_l[idx];
#pragma unroll
                for (int p = 0; p < 2; ++p) {
                    accS[mt][p] = __builtin_amdgcn_mfma_f32_16x16x32_bf16(ah, bS[p][ki][0], accS[mt][p], 0, 0, 0);
                    accS[mt][p] = __builtin_amdgcn_mfma_f32_16x16x32_bf16(al, bS[p][ki][0], accS[mt][p], 0, 0, 0);
                    accS[mt][p] = __builtin_amdgcn_mfma_f32_16x16x32_bf16(ah, bS[p][ki][1], accS[mt][p], 0, 0, 0);
                    accG[mt][p] = __builtin_amdgcn_mfma_f32_16x16x32_bf16(ah, bG[p][ki][0], accG[mt][p], 0, 0, 0);
                    accG[mt][p] = __builtin_amdgcn_mfma_f32_16x16x32_bf16(al, bG[p][ki][0], accG[mt][p], 0, 0, 0);
                    accG[mt][p] = __builtin_amdgcn_mfma_f32_16x16x32_bf16(ah, bG[p][ki][1], accG[mt][p], 0, 0, 0);
                }
            }
        }
        // pack (s,g) per lane, scattered store at sorted position
        const size_t e0 = (size_t)tile * 64;
#pragma unroll
        for (int mt = 0; mt < 4; ++mt) {
#pragma unroll
            for (int reg = 0; reg < 4; ++reg) {
                size_t e = e0 + mt * 16 + (lane >> 4) * 4 + reg;
                unsigned pos = inv[e];
#pragma unroll
                for (int p = 0; p < 2; ++p) {
                    unsigned val = pack_bf2(accS[mt][p][reg], accG[mt][p][reg]);
                    C32[(size_t)pos * 128 + (2 * w + p) * 16 + (lane & 15)] = val;
                }
            }
        }
    }
}

// ================= sorted apply =================
__device__ __forceinline__ void proc_edge(
    int src, uint2 cc, uint2 qq, uint2 pp,
    int& cur, uint2& pv, float& accA, float& accB,
    float bsA, float bsB, float bgA, float bgB,
    float* __restrict__ acc, int t)
{
    if (src != cur) {                                   // wave-uniform
        atomicAdd(&acc[(size_t)cur * AD + 2 * t],     accA);
        atomicAdd(&acc[(size_t)cur * AD + 2 * t + 1], accB);
        accA = 0.f; accB = 0.f; cur = src; pv = pp;
    }
    float sA = unp_lo(cc.x) + unp_lo(pv.x) + unp_lo(qq.x) + bsA;
    float gA = unp_hi(cc.x) + unp_hi(pv.x) + unp_hi(qq.x) + bgA;
    float sB = unp_lo(cc.y) + unp_lo(pv.y) + unp_lo(qq.y) + bsB;
    float gB = unp_hi(cc.y) + unp_hi(pv.y) + unp_hi(qq.y) + bgB;
    accA += msg_f(sA, gA);
    accB += msg_f(sB, gB);
}

__global__ void __launch_bounds__(256) edge_apply_sorted(
    const uint2* __restrict__ C64, const uint2* __restrict__ PQ64,
    const int* __restrict__ ssrc, const int* __restrict__ sdst,
    const float* __restrict__ bs, const float* __restrict__ bg,
    float* __restrict__ acc)
{
    __shared__ int s_src[4][64];
    __shared__ int s_dst[4][64];
    const int t = threadIdx.x & 63;
    const int w = threadIdx.x >> 6;
    const size_t p0 = ((size_t)blockIdx.x * 4 + w) * 64;
    s_src[w][t] = ssrc[p0 + t];
    s_dst[w][t] = sdst[p0 + t];
    __syncthreads();

    const float bsA = bs[2 * t], bsB = bs[2 * t + 1];
    const float bgA = bg[2 * t], bgB = bg[2 * t + 1];

    int cur = s_src[w][0];
    uint2 pv = PQ64[(size_t)cur * 128 + t];
    // depth-4 static rings: C stream, Q gather, P (for run transitions)
    uint2 c0 = C64[(p0 + 0) * 64 + t], c1 = C64[(p0 + 1) * 64 + t],
          c2 = C64[(p0 + 2) * 64 + t], c3 = C64[(p0 + 3) * 64 + t];
    uint2 q0 = PQ64[(size_t)s_dst[w][0] * 128 + 64 + t],
          q1 = PQ64[(size_t)s_dst[w][1] * 128 + 64 + t],
          q2 = PQ64[(size_t)s_dst[w][2] * 128 + 64 + t],
          q3 = PQ64[(size_t)s_dst[w][3] * 128 + 64 + t];
    uint2 r0 = PQ64[(size_t)s_src[w][0] * 128 + t],
          r1 = PQ64[(size_t)s_src[w][1] * 128 + t],
          r2 = PQ64[(size_t)s_src[w][2] * 128 + t],
          r3 = PQ64[(size_t)s_src[w][3] * 128 + t];
    float accA = 0.f, accB = 0.f;

    for (int j = 0; j < 16; ++j) {
        int b = 4 * j;
        proc_edge(s_src[w][b + 0], c0, q0, r0, cur, pv, accA, accB, bsA, bsB, bgA, bgB, acc, t);
        { int nx = (b + 4 < 64) ? b + 4 : 63;
          c0 = C64[(p0 + nx) * 64 + t];
          q0 = PQ64[(size_t)s_dst[w][nx] * 128 + 64 + t];
          r0 = PQ64[(size_t)s_src[w][nx] * 128 + t]; }
        proc_edge(s_src[w][b + 1], c1, q1, r1, cur, pv, accA, accB, bsA, bsB, bgA, bgB, acc, t);
        { int nx = (b + 5 < 64) ? b + 5 : 63;
          c1 = C64[(p0 + nx) * 64 + t];
          q1 = PQ64[(size_t)s_dst[w][nx] * 128 + 64 + t];
          r1 = PQ64[(size_t)s_src[w][nx] * 128 + t]; }
        proc_edge(s_src[w][b + 2], c2, q2, r2, cur, pv, accA, accB, bsA, bsB, bgA, bgB, acc, t);
        { int nx = (b + 6 < 64) ? b + 6 : 63;
          c2 = C64[(p0 + nx) * 64 + t];
          q2 = PQ64[(size_t)s_dst[w][nx] * 128 + 64 + t];
          r2 = PQ64[(size_t)s_src[w][nx] * 128 + t]; }
        proc_edge(s_src[w][b + 3], c3, q3, r3, cur, pv, accA, accB, bsA, bsB, bgA, bgB, acc, t);
        { int nx = (b + 7 < 64) ? b + 7 : 63;
          c3 = C64[(p0 + nx) * 64 + t];
          q3 = PQ64[(size_t)s_dst[w][nx] * 128 + 64 + t];
          r3 = PQ64[(size_t)s_src[w][nx] * 128 + t]; }
    }
    atomicAdd(&acc[(size_t)cur * AD + 2 * t],     accA);
    atomicAdd(&acc[(size_t)cur * AD + 2 * t + 1], accB);
}

// ================= softplus in place =================
__global__ void __launch_bounds__(256) act_k(float* __restrict__ acc)
{
    size_t i = ((size_t)blockIdx.x * 256 + threadIdx.x) * 4;
    float4 v = *(float4*)&acc[i];
    v.x = softplus_f(v.x);
    v.y = softplus_f(v.y);
    v.z = softplus_f(v.z);
    v.w = softplus_f(v.w);
    *(float4*)&acc[i] = v;
}

// ================= Tier B fallback (round-1, known good) =================
__global__ void __launch_bounds__(128) node_mm_f32(
    const float* __restrict__ x, const float* __restrict__ Ks,
    const float* __restrict__ Kg, float* __restrict__ PQ)
{
    __shared__ float xs[8][AD];
    const int t = threadIdx.x;
    const int row0 = blockIdx.x * 8;
#pragma unroll
    for (int r = 0; r < 8; ++r) xs[r][t] = x[(size_t)(row0 + r) * AD + t];
    __syncthreads();
    float aPs[8] = {}, aQs[8] = {}, aPg[8] = {}, aQg[8] = {};
    for (int k = 0; k < AD; ++k) {
        float ks_s = Ks[k * AD + t];
        float ks_d = Ks[(AD + k) * AD + t];
        float kg_s = Kg[k * AD + t];
        float kg_d = Kg[(AD + k) * AD + t];
#pragma unroll
        for (int r = 0; r < 8; ++r) {
            float xv = xs[r][k];
            aPs[r] = fmaf(xv, ks_s, aPs[r]);
            aQs[r] = fmaf(xv, ks_d, aQs[r]);
            aPg[r] = fmaf(xv, kg_s, aPg[r]);
            aQg[r] = fmaf(xv, kg_d, aQg[r]);
        }
    }
#pragma unroll
    for (int r = 0; r < 8; ++r) {
        float* o = PQ + (size_t)(row0 + r) * 512;
        *(float2*)&o[2 * t]       = make_float2(aPs[r], aPg[r]);
        *(float2*)&o[256 + 2 * t] = make_float2(aQs[r], aQg[r]);
    }
}

__global__ void __launch_bounds__(256) edge_fused(
    const float* __restrict__ ef, const float* __restrict__ Ks,
    const float* __restrict__ Kg, const float* __restrict__ PQ,
    const int* __restrict__ pidx, const float* __restrict__ bs,
    const float* __restrict__ bg, float* __restrict__ acc)
{
    __shared__ float KB[ED][2 * AD];
    __shared__ float es[64][ED];
    const int t = threadIdx.x;
    for (int i = t; i < ED * AD; i += 256) {
        int k = i >> 7, n = i & 127;
        KB[k][2 * n]     = Ks[(2 * AD + k) * AD + n];
        KB[k][2 * n + 1] = Kg[(2 * AD + k) * AD + n];
    }
    const size_t e0 = (size_t)blockIdx.x * 64;
    for (int i = t; i < 64 * ED; i += 256) ((float*)es)[i] = ef[e0 * ED + i];
    __syncthreads();
    const int le = t >> 7, n = t & 127;
    const float bsn = bs[n], bgn = bg[n];
    for (int base = le * 8; base < 64; base += 16) {
        float accS[8] = {}, accG[8] = {};
        for (int k4 = 0; k4 < ED / 4; ++k4) {
            float2 kv0 = *(const float2*)&KB[4 * k4 + 0][2 * n];
            float2 kv1 = *(const float2*)&KB[4 * k4 + 1][2 * n];
            float2 kv2 = *(const float2*)&KB[4 * k4 + 2][2 * n];
            float2 kv3 = *(const float2*)&KB[4 * k4 + 3][2 * n];
#pragma unroll
            for (int r = 0; r < 8; ++r) {
                float4 ev = *(const float4*)&es[base + r][4 * k4];
                accS[r] = fmaf(ev.x, kv0.x, accS[r]);
                accG[r] = fmaf(ev.x, kv0.y, accG[r]);
                accS[r] = fmaf(ev.y, kv1.x, accS[r]);
                accG[r] = fmaf(ev.y, kv1.y, accG[r]);
                accS[r] = fmaf(ev.z, kv2.x, accS[r]);
                accG[r] = fmaf(ev.z, kv2.y, accG[r]);
                accS[r] = fmaf(ev.w, kv3.x, accS[r]);
                accG[r] = fmaf(ev.w, kv3.y, accG[r]);
            }
        }
#pragma unroll
        for (int r = 0; r < 8; ++r) {
            size_t e = e0 + base + r;
            int src = pidx[2 * e], dst = pidx[2 * e + 1];
            float2 pv = *(const float2*)&PQ[(size_t)src * 512 + 2 * n];
            float2 qv = *(const float2*)&PQ[(size_t)dst * 512 + 256 + 2 * n];
            float s = accS[r] + pv.x + qv.x + bsn;
            float g = accG[r] + pv.y + qv.y + bgn;
            atomicAdd(&acc[(size_t)src * AD + n], sigmoid_fast(s) * softplus_f(g));
        }
    }
}

// ================= launch =================
extern "C" void kernel_launch(void* const* d_in, const int* in_sizes, int n_in,
                              void* d_out, int out_size, void* d_ws, size_t ws_size,
                              hipStream_t stream)
{
    const float* atom = (const float*)d_in[0];
    const float* ef   = (const float*)d_in[1];
    const float* Ks   = (const float*)d_in[3];
    const float* bs   = (const float*)d_in[4];
    const float* Kg   = (const float*)d_in[5];
    const float* bg   = (const float*)d_in[6];
    const int*   pidx = (const int*)d_in[7];

    float* acc = (float*)d_out;

    char* w = (char*)d_ws;
    const size_t PQ_B  = (size_t)NN * 256 * 4;   //  51.2 MB
    const size_t C_B   = (size_t)NE * 128 * 4;   // 409.6 MB
    const size_t CNT_B = (size_t)NN * 4;
    const size_t IDX_B = (size_t)NE * 4;
    unsigned* PQ32 = (unsigned*)w;  w += PQ_B;
    unsigned* C32  = (unsigned*)w;  w += C_B;
    unsigned* cnt  = (unsigned*)w;  w += CNT_B;
    unsigned* curp = (unsigned*)w;  w += CNT_B;
    unsigned* inv  = (unsigned*)w;  w += IDX_B;
    int*      ssrc = (int*)w;       w += IDX_B;
    int*      sdst = (int*)w;       w += IDX_B;
    const size_t TOTAL_A = PQ_B + C_B + 2 * CNT_B + 3 * IDX_B;

    hipMemcpyAsync(acc, atom, (size_t)NN * AD * sizeof(float),
                   hipMemcpyDeviceToDevice, stream);

    if (ws_size >= TOTAL_A) {
        hipMemsetAsync(cnt, 0, CNT_B, stream);
        hist_k<<<NE / 256, 256, 0, stream>>>(pidx, cnt);
        scan_k<<<1, 1024, 0, stream>>>(cnt, curp);
        scatter_k<<<NE / 256, 256, 0, stream>>>(pidx, curp, inv, ssrc, sdst);
        edge_c_mfma<<<512, 256, 0, stream>>>(ef, Ks, Kg, inv, C32);

        for (int s = 0; s < NSTEPS; ++s) {
            node_mm_b16<<<NN / 8, 128, 0, stream>>>(acc, Ks, Kg, PQ32);
            edge_apply_sorted<<<NE / 256, 256, 0, stream>>>(
                (const uint2*)C32, (const uint2*)PQ32, ssrc, sdst, bs, bg, acc);
            act_k<<<(NN * AD) / 1024, 256, 0, stream>>>(acc);
        }
    } else {
        float* PQ = (float*)d_ws;
        for (int s = 0; s < NSTEPS; ++s) {
            node_mm_f32<<<NN / 8, 128, 0, stream>>>(acc, Ks, Kg, PQ);
            edge_fused<<<NE / 64, 256, 0, stream>>>(ef, Ks, Kg, PQ, pidx, bs, bg, acc);
            act_k<<<(NN * AD) / 1024, 256, 0, stream>>>(acc);
        }
    }
}

// Round 4
// 1061.903 us; speedup vs baseline: 3.2632x; 1.2020x over previous
//
#include <hip/hip_runtime.h>
#include <hip/hip_bf16.h>
#include <math.h>

// CrystalGraphConvolution — MI355X round 4
// vs r3: hierarchical scan (was single-block), apply v2 (conditional P-ring,
// per-run hoisted pv+bias, nontemporal C loads), node_mm 16-row + float4 LDS
// broadcast, nontemporal C stores in edge_c_mfma.

#define NN 50000
#define NE 800000
#define AD 128
#define ED 64
#define NSTEPS 3
#define NTILES (NE / 64)          // 12500
#define NSCAN  ((NN + 255) / 256) // 196

typedef __attribute__((ext_vector_type(8))) __bf16 bf16x8;
typedef __attribute__((ext_vector_type(4))) float  f32x4;
typedef __attribute__((ext_vector_type(2))) unsigned u32x2;

__device__ __forceinline__ float sigmoid_fast(float x) {
    float e = __expf(-fabsf(x));
    float r = __builtin_amdgcn_rcpf(1.f + e);
    return (x >= 0.f) ? r : 1.f - r;
}
__device__ __forceinline__ float softplus_fast(float x) {
    return fmaxf(x, 0.f) + __logf(1.f + __expf(-fabsf(x)));
}
__device__ __forceinline__ float msg_f(float s, float g) {
    return sigmoid_fast(s) * softplus_fast(g);
}
__device__ __forceinline__ float softplus_f(float x) {  // precise (output path)
    return fmaxf(x, 0.f) + log1pf(__expf(-fabsf(x)));
}
__device__ __forceinline__ unsigned short bf16_rne(float f) {
    unsigned u = __float_as_uint(f);
    unsigned r = u + 0x7fffu + ((u >> 16) & 1u);
    return (unsigned short)(r >> 16);
}
__device__ __forceinline__ unsigned pack_bf2(float s, float g) {
    return (unsigned)bf16_rne(s) | ((unsigned)bf16_rne(g) << 16);
}
__device__ __forceinline__ float unp_lo(unsigned v) { return __uint_as_float(v << 16); }
__device__ __forceinline__ float unp_hi(unsigned v) { return __uint_as_float(v & 0xffff0000u); }

// ================= node projections (bf16 packed PQ) =================
__global__ void __launch_bounds__(128) node_mm_b16(
    const float* __restrict__ x, const float* __restrict__ Ks,
    const float* __restrict__ Kg, unsigned* __restrict__ PQ32)
{
    __shared__ float xs[16][AD];
    const int t = threadIdx.x;
    const int row0 = blockIdx.x * 16;
#pragma unroll
    for (int r = 0; r < 16; ++r) xs[r][t] = x[(size_t)(row0 + r) * AD + t];
    __syncthreads();

    float aPs[16] = {}, aQs[16] = {}, aPg[16] = {}, aQg[16] = {};
    for (int k4 = 0; k4 < AD / 4; ++k4) {
        const int k = 4 * k4;
        float ks_s[4], ks_d[4], kg_s[4], kg_d[4];
#pragma unroll
        for (int j = 0; j < 4; ++j) {
            ks_s[j] = Ks[(size_t)(k + j) * AD + t];
            ks_d[j] = Ks[(size_t)(AD + k + j) * AD + t];
            kg_s[j] = Kg[(size_t)(k + j) * AD + t];
            kg_d[j] = Kg[(size_t)(AD + k + j) * AD + t];
        }
#pragma unroll
        for (int r = 0; r < 16; ++r) {
            float4 xv = *(const float4*)&xs[r][k];   // b128 broadcast
            aPs[r] = fmaf(xv.x, ks_s[0], aPs[r]);
            aPs[r] = fmaf(xv.y, ks_s[1], aPs[r]);
            aPs[r] = fmaf(xv.z, ks_s[2], aPs[r]);
            aPs[r] = fmaf(xv.w, ks_s[3], aPs[r]);
            aQs[r] = fmaf(xv.x, ks_d[0], aQs[r]);
            aQs[r] = fmaf(xv.y, ks_d[1], aQs[r]);
            aQs[r] = fmaf(xv.z, ks_d[2], aQs[r]);
            aQs[r] = fmaf(xv.w, ks_d[3], aQs[r]);
            aPg[r] = fmaf(xv.x, kg_s[0], aPg[r]);
            aPg[r] = fmaf(xv.y, kg_s[1], aPg[r]);
            aPg[r] = fmaf(xv.z, kg_s[2], aPg[r]);
            aPg[r] = fmaf(xv.w, kg_s[3], aPg[r]);
            aQg[r] = fmaf(xv.x, kg_d[0], aQg[r]);
            aQg[r] = fmaf(xv.y, kg_d[1], aQg[r]);
            aQg[r] = fmaf(xv.z, kg_d[2], aQg[r]);
            aQg[r] = fmaf(xv.w, kg_d[3], aQg[r]);
        }
    }
#pragma unroll
    for (int r = 0; r < 16; ++r) {
        unsigned* o = PQ32 + (size_t)(row0 + r) * 256;
        o[t]       = pack_bf2(aPs[r], aPg[r]);
        o[128 + t] = pack_bf2(aQs[r], aQg[r]);
    }
}

// ================= sort machinery =================
__global__ void __launch_bounds__(256) hist_k(const int* __restrict__ pidx,
                                              unsigned* __restrict__ cnt)
{
    int e = blockIdx.x * 256 + threadIdx.x;
    atomicAdd(&cnt[pidx[2 * e]], 1u);
}

__global__ void __launch_bounds__(256) scan1_k(const unsigned* __restrict__ cnt,
                                               unsigned* __restrict__ cur,
                                               unsigned* __restrict__ part)
{
    __shared__ unsigned tmp[256];
    const int t = threadIdx.x;
    const int bin = blockIdx.x * 256 + t;
    unsigned v = (bin < NN) ? cnt[bin] : 0u;
    tmp[t] = v;
    __syncthreads();
    for (int off = 1; off < 256; off <<= 1) {
        unsigned a = (t >= off) ? tmp[t - off] : 0u;
        __syncthreads();
        tmp[t] += a;
        __syncthreads();
    }
    if (bin < NN) cur[bin] = tmp[t] - v;       // local exclusive
    if (t == 255) part[blockIdx.x] = tmp[255]; // chunk total
}

__global__ void __launch_bounds__(256) scan2_k(unsigned* __restrict__ part)
{
    __shared__ unsigned tmp[256];
    const int t = threadIdx.x;
    unsigned v = (t < NSCAN) ? part[t] : 0u;
    tmp[t] = v;
    __syncthreads();
    for (int off = 1; off < 256; off <<= 1) {
        unsigned a = (t >= off) ? tmp[t - off] : 0u;
        __syncthreads();
        tmp[t] += a;
        __syncthreads();
    }
    if (t < NSCAN) part[t] = tmp[t] - v;       // exclusive chunk offsets
}

__global__ void __launch_bounds__(256) scan3_k(unsigned* __restrict__ cur,
                                               const unsigned* __restrict__ part)
{
    const int bin = blockIdx.x * 256 + threadIdx.x;
    if (bin < NN) cur[bin] += part[blockIdx.x];
}

__global__ void __launch_bounds__(256) scatter_k(
    const int* __restrict__ pidx, unsigned* __restrict__ cur,
    unsigned* __restrict__ inv, int* __restrict__ ssrc, int* __restrict__ sdst)
{
    int e = blockIdx.x * 256 + threadIdx.x;
    int s = pidx[2 * e], d = pidx[2 * e + 1];
    unsigned pos = atomicAdd(&cur[s], 1u);
    inv[e] = pos;
    ssrc[pos] = s;
    sdst[pos] = d;
}

// ================= C = ef @ K_bot via MFMA (hi/lo split) =================
__global__ void __launch_bounds__(256) edge_c_mfma(
    const float* __restrict__ ef, const float* __restrict__ Ks,
    const float* __restrict__ Kg, const unsigned* __restrict__ inv,
    unsigned* __restrict__ C32)
{
    __shared__ short As_h[64 * 64];
    __shared__ short As_l[64 * 64];
    __shared__ short Bt[4][128 * 64];   // 0=Sh 1=Sl 2=Gh 3=Gl
    const int t = threadIdx.x;
    const int w = t >> 6, lane = t & 63;

    for (int i = t; i < 64 * 128; i += 256) {
        int k = i >> 7, n = i & 127;
        float vs = Ks[(size_t)(2 * AD + k) * AD + n];
        float vg = Kg[(size_t)(2 * AD + k) * AD + n];
        int sidx = (n * 64 + k) ^ ((n & 7) << 3);
        unsigned short sh = bf16_rne(vs);
        unsigned short sl = bf16_rne(vs - __uint_as_float((unsigned)sh << 16));
        unsigned short gh = bf16_rne(vg);
        unsigned short gl = bf16_rne(vg - __uint_as_float((unsigned)gh << 16));
        Bt[0][sidx] = (short)sh; Bt[1][sidx] = (short)sl;
        Bt[2][sidx] = (short)gh; Bt[3][sidx] = (short)gl;
    }
    __syncthreads();

    bf16x8 bS[2][2][2], bG[2][2][2];
#pragma unroll
    for (int p = 0; p < 2; ++p) {
        int col = (2 * w + p) * 16 + (lane & 15);
#pragma unroll
        for (int ki = 0; ki < 2; ++ki) {
            int idx = (col * 64 + ki * 32 + (lane >> 4) * 8) ^ ((col & 7) << 3);
            bS[p][ki][0] = *(const bf16x8*)&Bt[0][idx];
            bS[p][ki][1] = *(const bf16x8*)&Bt[1][idx];
            bG[p][ki][0] = *(const bf16x8*)&Bt[2][idx];
            bG[p][ki][1] = *(const bf16x8*)&Bt[3][idx];
        }
    }

    float4 pf0, pf1, pf2, pf3;
    {
        const float4* src = (const float4*)(ef + (size_t)blockIdx.x * 64 * 64);
        if (blockIdx.x < NTILES) {
            pf0 = src[t]; pf1 = src[t + 256]; pf2 = src[t + 512]; pf3 = src[t + 768];
        }
    }

    for (int tile = blockIdx.x; tile < NTILES; tile += gridDim.x) {
        __syncthreads();
        {
            float4 v[4] = {pf0, pf1, pf2, pf3};
#pragma unroll
            for (int ii = 0; ii < 4; ++ii) {
                int i = t + 256 * ii, row = i >> 4, c4 = i & 15;
                float a0 = v[ii].x, a1 = v[ii].y, a2 = v[ii].z, a3 = v[ii].w;
                unsigned short h0 = bf16_rne(a0), h1 = bf16_rne(a1),
                               h2 = bf16_rne(a2), h3 = bf16_rne(a3);
                unsigned short l0 = bf16_rne(a0 - __uint_as_float((unsigned)h0 << 16));
                unsigned short l1 = bf16_rne(a1 - __uint_as_float((unsigned)h1 << 16));
                unsigned short l2 = bf16_rne(a2 - __uint_as_float((unsigned)h2 << 16));
                unsigned short l3 = bf16_rne(a3 - __uint_as_float((unsigned)h3 << 16));
                int sidx = (row * 64 + c4 * 4) ^ ((row & 7) << 3);
                *(short4*)&As_h[sidx] = make_short4((short)h0, (short)h1, (short)h2, (short)h3);
                *(short4*)&As_l[sidx] = make_short4((short)l0, (short)l1, (short)l2, (short)l3);
            }
        }
        {
            int nxt = tile + gridDim.x;
            if (nxt < NTILES) {
                const float4* src = (const float4*)(ef + (size_t)nxt * 64 * 64);
                pf0 = src[t]; pf1 = src[t + 256]; pf2 = src[t + 512]; pf3 = src[t + 768];
            }
        }
        __syncthreads();

        f32x4 accS[4][2] = {}, accG[4][2] = {};
#pragma unroll
        for (int mt = 0; mt < 4; ++mt) {
#pragma unroll
            for (int ki = 0; ki < 2; ++ki) {
                int row = mt * 16 + (lane & 15);
                int idx = (row * 64 + ki * 32 + (lane >> 4) * 8) ^ ((row & 7) << 3);
                bf16x8 ah = *(const bf16x8*)&As_h[idx];
                bf16x8 al = *(const bf16x8*)&As_l[idx];
#pragma unroll
                for (int p = 0; p < 2; ++p) {
                    accS[mt][p] = __builtin_amdgcn_mfma_f32_16x16x32_bf16(ah, bS[p][ki][0], accS[mt][p], 0, 0, 0);
                    accS[mt][p] = __builtin_amdgcn_mfma_f32_16x16x32_bf16(al, bS[p][ki][0], accS[mt][p], 0, 0, 0);
                    accS[mt][p] = __builtin_amdgcn_mfma_f32_16x16x32_bf16(ah, bS[p][ki][1], accS[mt][p], 0, 0, 0);
                    accG[mt][p] = __builtin_amdgcn_mfma_f32_16x16x32_bf16(ah, bG[p][ki][0], accG[mt][p], 0, 0, 0);
                    accG[mt][p] = __builtin_amdgcn_mfma_f32_16x16x32_bf16(al, bG[p][ki][0], accG[mt][p], 0, 0, 0);
                    accG[mt][p] = __builtin_amdgcn_mfma_f32_16x16x32_bf16(ah, bG[p][ki][1], accG[mt][p], 0, 0, 0);
                }
            }
        }
        const size_t e0 = (size_t)tile * 64;
#pragma unroll
        for (int mt = 0; mt < 4; ++mt) {
#pragma unroll
            for (int reg = 0; reg < 4; ++reg) {
                size_t e = e0 + mt * 16 + (lane >> 4) * 4 + reg;
                unsigned pos = inv[e];
#pragma unroll
                for (int p = 0; p < 2; ++p) {
                    unsigned val = pack_bf2(accS[mt][p][reg], accG[mt][p][reg]);
                    __builtin_nontemporal_store(val,
                        &C32[(size_t)pos * 128 + (2 * w + p) * 16 + (lane & 15)]);
                }
            }
        }
    }
}

// ================= sorted apply v2 =================
__global__ void __launch_bounds__(256) edge_apply_sorted(
    const u32x2* __restrict__ C64, const u32x2* __restrict__ PQ64,
    const int* __restrict__ ssrc, const int* __restrict__ sdst,
    const float* __restrict__ bs, const float* __restrict__ bg,
    float* __restrict__ acc)
{
    __shared__ int s_src[4][64];
    __shared__ int s_dst[4][64];
    const int t = threadIdx.x & 63;
    const int w = threadIdx.x >> 6;
    const size_t p0 = ((size_t)blockIdx.x * 4 + w) * 64;
    s_src[w][t] = ssrc[p0 + t];
    s_dst[w][t] = sdst[p0 + t];
    __syncthreads();

    const float2 bsv = *(const float2*)&bs[2 * t];
    const float2 bgv = *(const float2*)&bg[2 * t];

    int cur = s_src[w][0];
    u32x2 pv = PQ64[(size_t)cur * 128 + t];
    float psA = unp_lo(pv.x) + bsv.x, pgA = unp_hi(pv.x) + bgv.x;
    float psB = unp_lo(pv.y) + bsv.y, pgB = unp_hi(pv.y) + bgv.y;

    // depth-4 rings: C stream (nontemporal), Q gather, conditional P
    u32x2 c0 = __builtin_nontemporal_load(&C64[(p0 + 0) * 64 + t]);
    u32x2 c1 = __builtin_nontemporal_load(&C64[(p0 + 1) * 64 + t]);
    u32x2 c2 = __builtin_nontemporal_load(&C64[(p0 + 2) * 64 + t]);
    u32x2 c3 = __builtin_nontemporal_load(&C64[(p0 + 3) * 64 + t]);
    u32x2 q0 = PQ64[(size_t)s_dst[w][0] * 128 + 64 + t];
    u32x2 q1 = PQ64[(size_t)s_dst[w][1] * 128 + 64 + t];
    u32x2 q2 = PQ64[(size_t)s_dst[w][2] * 128 + 64 + t];
    u32x2 q3 = PQ64[(size_t)s_dst[w][3] * 128 + 64 + t];
    u32x2 r0 = pv, r1 = pv, r2 = pv, r3 = pv;
    if (s_src[w][1] != s_src[w][0]) r1 = PQ64[(size_t)s_src[w][1] * 128 + t];
    if (s_src[w][2] != s_src[w][1]) r2 = PQ64[(size_t)s_src[w][2] * 128 + t];
    if (s_src[w][3] != s_src[w][2]) r3 = PQ64[(size_t)s_src[w][3] * 128 + t];
    float accA = 0.f, accB = 0.f;

#define PROC_CORE(i, cc, qq, rr)                                           \
    {                                                                      \
        int src_ = s_src[w][(i)];                                          \
        if (src_ != cur) {                                                 \
            atomicAdd(&acc[(size_t)cur * AD + 2 * t],     accA);           \
            atomicAdd(&acc[(size_t)cur * AD + 2 * t + 1], accB);           \
            accA = 0.f; accB = 0.f; cur = src_;                            \
            psA = unp_lo(rr.x) + bsv.x; pgA = unp_hi(rr.x) + bgv.x;        \
            psB = unp_lo(rr.y) + bsv.y; pgB = unp_hi(rr.y) + bgv.y;        \
        }                                                                  \
        float sA = unp_lo(cc.x) + unp_lo(qq.x) + psA;                      \
        float gA = unp_hi(cc.x) + unp_hi(qq.x) + pgA;                      \
        float sB = unp_lo(cc.y) + unp_lo(qq.y) + psB;                      \
        float gB = unp_hi(cc.y) + unp_hi(qq.y) + pgB;                      \
        accA += msg_f(sA, gA);                                             \
        accB += msg_f(sB, gB);                                             \
    }

#define PROC(i, cc, qq, rr)                                                \
    PROC_CORE(i, cc, qq, rr)                                               \
    {                                                                      \
        int nx_ = (i) + 4;                                                 \
        cc = __builtin_nontemporal_load(&C64[(p0 + nx_) * 64 + t]);        \
        qq = PQ64[(size_t)s_dst[w][nx_] * 128 + 64 + t];                   \
        if (s_src[w][nx_] != s_src[w][nx_ - 1])                            \
            rr = PQ64[(size_t)s_src[w][nx_] * 128 + t];                    \
    }

    for (int j = 0; j < 15; ++j) {
        int b = 4 * j;
        PROC(b + 0, c0, q0, r0)
        PROC(b + 1, c1, q1, r1)
        PROC(b + 2, c2, q2, r2)
        PROC(b + 3, c3, q3, r3)
    }
    PROC_CORE(60, c0, q0, r0)
    PROC_CORE(61, c1, q1, r1)
    PROC_CORE(62, c2, q2, r2)
    PROC_CORE(63, c3, q3, r3)

    atomicAdd(&acc[(size_t)cur * AD + 2 * t],     accA);
    atomicAdd(&acc[(size_t)cur * AD + 2 * t + 1], accB);
#undef PROC
#undef PROC_CORE
}

// ================= softplus in place =================
__global__ void __launch_bounds__(256) act_k(float* __restrict__ acc)
{
    size_t i = ((size_t)blockIdx.x * 256 + threadIdx.x) * 4;
    float4 v = *(float4*)&acc[i];
    v.x = softplus_f(v.x);
    v.y = softplus_f(v.y);
    v.z = softplus_f(v.z);
    v.w = softplus_f(v.w);
    *(float4*)&acc[i] = v;
}

// ================= Tier B fallback (round-1, known good) =================
__global__ void __launch_bounds__(128) node_mm_f32(
    const float* __restrict__ x, const float* __restrict__ Ks,
    const float* __restrict__ Kg, float* __restrict__ PQ)
{
    __shared__ float xs[8][AD];
    const int t = threadIdx.x;
    const int row0 = blockIdx.x * 8;
#pragma unroll
    for (int r = 0; r < 8; ++r) xs[r][t] = x[(size_t)(row0 + r) * AD + t];
    __syncthreads();
    float aPs[8] = {}, aQs[8] = {}, aPg[8] = {}, aQg[8] = {};
    for (int k = 0; k < AD; ++k) {
        float ks_s = Ks[k * AD + t];
        float ks_d = Ks[(AD + k) * AD + t];
        float kg_s = Kg[k * AD + t];
        float kg_d = Kg[(AD + k) * AD + t];
#pragma unroll
        for (int r = 0; r < 8; ++r) {
            float xv = xs[r][k];
            aPs[r] = fmaf(xv, ks_s, aPs[r]);
            aQs[r] = fmaf(xv, ks_d, aQs[r]);
            aPg[r] = fmaf(xv, kg_s, aPg[r]);
            aQg[r] = fmaf(xv, kg_d, aQg[r]);
        }
    }
#pragma unroll
    for (int r = 0; r < 8; ++r) {
        float* o = PQ + (size_t)(row0 + r) * 512;
        *(float2*)&o[2 * t]       = make_float2(aPs[r], aPg[r]);
        *(float2*)&o[256 + 2 * t] = make_float2(aQs[r], aQg[r]);
    }
}

__global__ void __launch_bounds__(256) edge_fused(
    const float* __restrict__ ef, const float* __restrict__ Ks,
    const float* __restrict__ Kg, const float* __restrict__ PQ,
    const int* __restrict__ pidx, const float* __restrict__ bs,
    const float* __restrict__ bg, float* __restrict__ acc)
{
    __shared__ float KB[ED][2 * AD];
    __shared__ float es[64][ED];
    const int t = threadIdx.x;
    for (int i = t; i < ED * AD; i += 256) {
        int k = i >> 7, n = i & 127;
        KB[k][2 * n]     = Ks[(2 * AD + k) * AD + n];
        KB[k][2 * n + 1] = Kg[(2 * AD + k) * AD + n];
    }
    const size_t e0 = (size_t)blockIdx.x * 64;
    for (int i = t; i < 64 * ED; i += 256) ((float*)es)[i] = ef[e0 * ED + i];
    __syncthreads();
    const int le = t >> 7, n = t & 127;
    const float bsn = bs[n], bgn = bg[n];
    for (int base = le * 8; base < 64; base += 16) {
        float accS[8] = {}, accG[8] = {};
        for (int k4 = 0; k4 < ED / 4; ++k4) {
            float2 kv0 = *(const float2*)&KB[4 * k4 + 0][2 * n];
            float2 kv1 = *(const float2*)&KB[4 * k4 + 1][2 * n];
            float2 kv2 = *(const float2*)&KB[4 * k4 + 2][2 * n];
            float2 kv3 = *(const float2*)&KB[4 * k4 + 3][2 * n];
#pragma unroll
            for (int r = 0; r < 8; ++r) {
                float4 ev = *(const float4*)&es[base + r][4 * k4];
                accS[r] = fmaf(ev.x, kv0.x, accS[r]);
                accG[r] = fmaf(ev.x, kv0.y, accG[r]);
                accS[r] = fmaf(ev.y, kv1.x, accS[r]);
                accG[r] = fmaf(ev.y, kv1.y, accG[r]);
                accS[r] = fmaf(ev.z, kv2.x, accS[r]);
                accG[r] = fmaf(ev.z, kv2.y, accG[r]);
                accS[r] = fmaf(ev.w, kv3.x, accS[r]);
                accG[r] = fmaf(ev.w, kv3.y, accG[r]);
            }
        }
#pragma unroll
        for (int r = 0; r < 8; ++r) {
            size_t e = e0 + base + r;
            int src = pidx[2 * e], dst = pidx[2 * e + 1];
            float2 pv = *(const float2*)&PQ[(size_t)src * 512 + 2 * n];
            float2 qv = *(const float2*)&PQ[(size_t)dst * 512 + 256 + 2 * n];
            float s = accS[r] + pv.x + qv.x + bsn;
            float g = accG[r] + pv.y + qv.y + bgn;
            atomicAdd(&acc[(size_t)src * AD + n], sigmoid_fast(s) * softplus_f(g));
        }
    }
}

// ================= launch =================
extern "C" void kernel_launch(void* const* d_in, const int* in_sizes, int n_in,
                              void* d_out, int out_size, void* d_ws, size_t ws_size,
                              hipStream_t stream)
{
    const float* atom = (const float*)d_in[0];
    const float* ef   = (const float*)d_in[1];
    const float* Ks   = (const float*)d_in[3];
    const float* bs   = (const float*)d_in[4];
    const float* Kg   = (const float*)d_in[5];
    const float* bg   = (const float*)d_in[6];
    const int*   pidx = (const int*)d_in[7];

    float* acc = (float*)d_out;

    char* w = (char*)d_ws;
    const size_t PQ_B   = (size_t)NN * 256 * 4;   //  51.2 MB
    const size_t C_B    = (size_t)NE * 128 * 4;   // 409.6 MB
    const size_t CNT_B  = (size_t)NN * 4;
    const size_t IDX_B  = (size_t)NE * 4;
    const size_t PART_B = 256 * 4;
    unsigned* PQ32 = (unsigned*)w;  w += PQ_B;
    unsigned* C32  = (unsigned*)w;  w += C_B;
    unsigned* cnt  = (unsigned*)w;  w += CNT_B;
    unsigned* curp = (unsigned*)w;  w += CNT_B;
    unsigned* inv  = (unsigned*)w;  w += IDX_B;
    int*      ssrc = (int*)w;       w += IDX_B;
    int*      sdst = (int*)w;       w += IDX_B;
    unsigned* part = (unsigned*)w;  w += PART_B;
    const size_t TOTAL_A = PQ_B + C_B + 2 * CNT_B + 3 * IDX_B + PART_B;

    hipMemcpyAsync(acc, atom, (size_t)NN * AD * sizeof(float),
                   hipMemcpyDeviceToDevice, stream);

    if (ws_size >= TOTAL_A) {
        hipMemsetAsync(cnt, 0, CNT_B, stream);
        hist_k<<<NE / 256, 256, 0, stream>>>(pidx, cnt);
        scan1_k<<<NSCAN, 256, 0, stream>>>(cnt, curp, part);
        scan2_k<<<1, 256, 0, stream>>>(part);
        scan3_k<<<NSCAN, 256, 0, stream>>>(curp, part);
        scatter_k<<<NE / 256, 256, 0, stream>>>(pidx, curp, inv, ssrc, sdst);
        edge_c_mfma<<<512, 256, 0, stream>>>(ef, Ks, Kg, inv, C32);

        for (int s = 0; s < NSTEPS; ++s) {
            node_mm_b16<<<NN / 16, 128, 0, stream>>>(acc, Ks, Kg, PQ32);
            edge_apply_sorted<<<NE / 256, 256, 0, stream>>>(
                (const u32x2*)C32, (const u32x2*)PQ32, ssrc, sdst, bs, bg, acc);
            act_k<<<(NN * AD) / 1024, 256, 0, stream>>>(acc);
        }
    } else {
        float* PQ = (float*)d_ws;
        for (int s = 0; s < NSTEPS; ++s) {
            node_mm_f32<<<NN / 8, 128, 0, stream>>>(acc, Ks, Kg, PQ);
            edge_fused<<<NE / 64, 256, 0, stream>>>(ef, Ks, Kg, PQ, pidx, bs, bg, acc);
            act_k<<<(NN * AD) / 1024, 256, 0, stream>>>(acc);
        }
    }
}

// Round 5
// 998.306 us; speedup vs baseline: 3.4710x; 1.0637x over previous
//
#include <hip/hip_runtime.h>
#include <hip/hip_bf16.h>
#include <math.h>

// CrystalGraphConvolution — MI355X round 5
// vs r4: edge_c v3 — gather ef rows via sid (read-side permutation), LINEAR
// nontemporal C writes (was scattered), B fragments direct from global (no
// 64KB Bt LDS -> 16KB total, occupancy 20%->~50%). act_k + init memcpy folded
// into node_mm (copy-through / softplus-writeback modes); one final act.

#define NN 50000
#define NE 800000
#define AD 128
#define ED 64
#define NSTEPS 3
#define NTILES (NE / 64)          // 12500
#define NSCAN  ((NN + 255) / 256) // 196

typedef __attribute__((ext_vector_type(8))) __bf16 bf16x8;
typedef __attribute__((ext_vector_type(4))) float  f32x4;
typedef __attribute__((ext_vector_type(2))) unsigned u32x2;

__device__ __forceinline__ float sigmoid_fast(float x) {
    float e = __expf(-fabsf(x));
    float r = __builtin_amdgcn_rcpf(1.f + e);
    return (x >= 0.f) ? r : 1.f - r;
}
__device__ __forceinline__ float softplus_fast(float x) {
    return fmaxf(x, 0.f) + __logf(1.f + __expf(-fabsf(x)));
}
__device__ __forceinline__ float msg_f(float s, float g) {
    return sigmoid_fast(s) * softplus_fast(g);
}
__device__ __forceinline__ float softplus_f(float x) {  // precise (output path)
    return fmaxf(x, 0.f) + log1pf(__expf(-fabsf(x)));
}
__device__ __forceinline__ unsigned short bf16_rne(float f) {
    unsigned u = __float_as_uint(f);
    unsigned r = u + 0x7fffu + ((u >> 16) & 1u);
    return (unsigned short)(r >> 16);
}
__device__ __forceinline__ unsigned pack_bf2(float s, float g) {
    return (unsigned)bf16_rne(s) | ((unsigned)bf16_rne(g) << 16);
}
__device__ __forceinline__ float unp_lo(unsigned v) { return __uint_as_float(v << 16); }
__device__ __forceinline__ float unp_hi(unsigned v) { return __uint_as_float(v & 0xffff0000u); }

// ===== node projections (bf16 packed PQ) + x maintenance =====
// mode 0: xs = xin, acc = xin (copy-through, step 0)
// mode 1: xs = softplus(acc), acc = xs (fold act of previous step)
__global__ void __launch_bounds__(128) node_mm_b16(
    const float* __restrict__ xin, float* __restrict__ acc,
    const float* __restrict__ Ks, const float* __restrict__ Kg,
    unsigned* __restrict__ PQ32, int mode)
{
    __shared__ float xs[16][AD];
    const int t = threadIdx.x;
    const int row0 = blockIdx.x * 16;
    if (mode == 0) {
#pragma unroll
        for (int r = 0; r < 16; ++r) {
            float v = xin[(size_t)(row0 + r) * AD + t];
            xs[r][t] = v;
            acc[(size_t)(row0 + r) * AD + t] = v;
        }
    } else {
#pragma unroll
        for (int r = 0; r < 16; ++r) {
            float v = softplus_f(acc[(size_t)(row0 + r) * AD + t]);
            xs[r][t] = v;
            acc[(size_t)(row0 + r) * AD + t] = v;
        }
    }
    __syncthreads();

    float aPs[16] = {}, aQs[16] = {}, aPg[16] = {}, aQg[16] = {};
    for (int k4 = 0; k4 < AD / 4; ++k4) {
        const int k = 4 * k4;
        float ks_s[4], ks_d[4], kg_s[4], kg_d[4];
#pragma unroll
        for (int j = 0; j < 4; ++j) {
            ks_s[j] = Ks[(size_t)(k + j) * AD + t];
            ks_d[j] = Ks[(size_t)(AD + k + j) * AD + t];
            kg_s[j] = Kg[(size_t)(k + j) * AD + t];
            kg_d[j] = Kg[(size_t)(AD + k + j) * AD + t];
        }
#pragma unroll
        for (int r = 0; r < 16; ++r) {
            float4 xv = *(const float4*)&xs[r][k];
            aPs[r] = fmaf(xv.x, ks_s[0], aPs[r]);
            aPs[r] = fmaf(xv.y, ks_s[1], aPs[r]);
            aPs[r] = fmaf(xv.z, ks_s[2], aPs[r]);
            aPs[r] = fmaf(xv.w, ks_s[3], aPs[r]);
            aQs[r] = fmaf(xv.x, ks_d[0], aQs[r]);
            aQs[r] = fmaf(xv.y, ks_d[1], aQs[r]);
            aQs[r] = fmaf(xv.z, ks_d[2], aQs[r]);
            aQs[r] = fmaf(xv.w, ks_d[3], aQs[r]);
            aPg[r] = fmaf(xv.x, kg_s[0], aPg[r]);
            aPg[r] = fmaf(xv.y, kg_s[1], aPg[r]);
            aPg[r] = fmaf(xv.z, kg_s[2], aPg[r]);
            aPg[r] = fmaf(xv.w, kg_s[3], aPg[r]);
            aQg[r] = fmaf(xv.x, kg_d[0], aQg[r]);
            aQg[r] = fmaf(xv.y, kg_d[1], aQg[r]);
            aQg[r] = fmaf(xv.z, kg_d[2], aQg[r]);
            aQg[r] = fmaf(xv.w, kg_d[3], aQg[r]);
        }
    }
#pragma unroll
    for (int r = 0; r < 16; ++r) {
        unsigned* o = PQ32 + (size_t)(row0 + r) * 256;
        o[t]       = pack_bf2(aPs[r], aPg[r]);
        o[128 + t] = pack_bf2(aQs[r], aQg[r]);
    }
}

// ===== sort machinery =====
__global__ void __launch_bounds__(256) hist_k(const int* __restrict__ pidx,
                                              unsigned* __restrict__ cnt)
{
    int e = blockIdx.x * 256 + threadIdx.x;
    atomicAdd(&cnt[pidx[2 * e]], 1u);
}

__global__ void __launch_bounds__(256) scan1_k(const unsigned* __restrict__ cnt,
                                               unsigned* __restrict__ cur,
                                               unsigned* __restrict__ part)
{
    __shared__ unsigned tmp[256];
    const int t = threadIdx.x;
    const int bin = blockIdx.x * 256 + t;
    unsigned v = (bin < NN) ? cnt[bin] : 0u;
    tmp[t] = v;
    __syncthreads();
    for (int off = 1; off < 256; off <<= 1) {
        unsigned a = (t >= off) ? tmp[t - off] : 0u;
        __syncthreads();
        tmp[t] += a;
        __syncthreads();
    }
    if (bin < NN) cur[bin] = tmp[t] - v;
    if (t == 255) part[blockIdx.x] = tmp[255];
}

__global__ void __launch_bounds__(256) scan2_k(unsigned* __restrict__ part)
{
    __shared__ unsigned tmp[256];
    const int t = threadIdx.x;
    unsigned v = (t < NSCAN) ? part[t] : 0u;
    tmp[t] = v;
    __syncthreads();
    for (int off = 1; off < 256; off <<= 1) {
        unsigned a = (t >= off) ? tmp[t - off] : 0u;
        __syncthreads();
        tmp[t] += a;
        __syncthreads();
    }
    if (t < NSCAN) part[t] = tmp[t] - v;
}

__global__ void __launch_bounds__(256) scan3_k(unsigned* __restrict__ cur,
                                               const unsigned* __restrict__ part)
{
    const int bin = blockIdx.x * 256 + threadIdx.x;
    if (bin < NN) cur[bin] += part[blockIdx.x];
}

__global__ void __launch_bounds__(256) scatter_k(
    const int* __restrict__ pidx, unsigned* __restrict__ cur,
    int* __restrict__ sid, int* __restrict__ ssrc, int* __restrict__ sdst)
{
    int e = blockIdx.x * 256 + threadIdx.x;
    int s = pidx[2 * e], d = pidx[2 * e + 1];
    unsigned pos = atomicAdd(&cur[s], 1u);
    sid[pos] = e;
    ssrc[pos] = s;
    sdst[pos] = d;
}

// ===== C = ef @ K_bot via MFMA (hi/lo split), gather-read / linear-write =====
// 512 thr = 8 waves, 16 cols/wave. LDS = 16 KB (As hi/lo only); B fragments
// built directly from global K (one-time per block).
__global__ void __launch_bounds__(512) edge_c_mfma(
    const float* __restrict__ ef, const float* __restrict__ Ks,
    const float* __restrict__ Kg, const int* __restrict__ sid,
    unsigned* __restrict__ C32)
{
    __shared__ short As_h[64 * 64];
    __shared__ short As_l[64 * 64];
    const int t = threadIdx.x;
    const int w = t >> 6, lane = t & 63;

    // B fragments: col = w*16 + (lane&15); k = 2*AD + ki*32 + (lane>>4)*8 + j
    union U8 { short s[8]; bf16x8 v; };
    bf16x8 bS[2][2], bG[2][2];   // [ki][hi/lo]
    {
        const int col = w * 16 + (lane & 15);
#pragma unroll
        for (int ki = 0; ki < 2; ++ki) {
            U8 sh_, sl_, gh_, gl_;
            const int kbase = 2 * AD + ki * 32 + (lane >> 4) * 8;
#pragma unroll
            for (int j = 0; j < 8; ++j) {
                float vs = Ks[(size_t)(kbase + j) * AD + col];
                float vg = Kg[(size_t)(kbase + j) * AD + col];
                unsigned short h = bf16_rne(vs);
                sh_.s[j] = (short)h;
                sl_.s[j] = (short)bf16_rne(vs - __uint_as_float((unsigned)h << 16));
                h = bf16_rne(vg);
                gh_.s[j] = (short)h;
                gl_.s[j] = (short)bf16_rne(vg - __uint_as_float((unsigned)h << 16));
            }
            bS[ki][0] = sh_.v; bS[ki][1] = sl_.v;
            bG[ki][0] = gh_.v; bG[ki][1] = gl_.v;
        }
    }

    const int srow = t >> 4, sc4 = t & 15;   // staging: rows srow, srow+32
    float4 pf0, pf1;
    {
        int ea = sid[(size_t)blockIdx.x * 64 + srow];
        int eb = sid[(size_t)blockIdx.x * 64 + srow + 32];
        pf0 = *(const float4*)&ef[(size_t)ea * 64 + 4 * sc4];
        pf1 = *(const float4*)&ef[(size_t)eb * 64 + 4 * sc4];
    }

    for (int tile = blockIdx.x; tile < NTILES; tile += gridDim.x) {
        __syncthreads();   // previous tile's MFMA reads of As done
        {
            float4 v[2] = {pf0, pf1};
#pragma unroll
            for (int ii = 0; ii < 2; ++ii) {
                int row = srow + 32 * ii;
                float a0 = v[ii].x, a1 = v[ii].y, a2 = v[ii].z, a3 = v[ii].w;
                unsigned short h0 = bf16_rne(a0), h1 = bf16_rne(a1),
                               h2 = bf16_rne(a2), h3 = bf16_rne(a3);
                unsigned short l0 = bf16_rne(a0 - __uint_as_float((unsigned)h0 << 16));
                unsigned short l1 = bf16_rne(a1 - __uint_as_float((unsigned)h1 << 16));
                unsigned short l2 = bf16_rne(a2 - __uint_as_float((unsigned)h2 << 16));
                unsigned short l3 = bf16_rne(a3 - __uint_as_float((unsigned)h3 << 16));
                int sidx = (row * 64 + sc4 * 4) ^ ((row & 7) << 3);
                *(short4*)&As_h[sidx] = make_short4((short)h0, (short)h1, (short)h2, (short)h3);
                *(short4*)&As_l[sidx] = make_short4((short)l0, (short)l1, (short)l2, (short)l3);
            }
        }
        {
            int nxt = tile + gridDim.x;
            if (nxt < NTILES) {
                int ea = sid[(size_t)nxt * 64 + srow];
                int eb = sid[(size_t)nxt * 64 + srow + 32];
                pf0 = *(const float4*)&ef[(size_t)ea * 64 + 4 * sc4];
                pf1 = *(const float4*)&ef[(size_t)eb * 64 + 4 * sc4];
            }
        }
        __syncthreads();

        f32x4 accS[4] = {}, accG[4] = {};
#pragma unroll
        for (int mt = 0; mt < 4; ++mt) {
#pragma unroll
            for (int ki = 0; ki < 2; ++ki) {
                int row = mt * 16 + (lane & 15);
                int idx = (row * 64 + ki * 32 + (lane >> 4) * 8) ^ ((row & 7) << 3);
                bf16x8 ah = *(const bf16x8*)&As_h[idx];
                bf16x8 al = *(const bf16x8*)&As_l[idx];
                accS[mt] = __builtin_amdgcn_mfma_f32_16x16x32_bf16(ah, bS[ki][0], accS[mt], 0, 0, 0);
                accS[mt] = __builtin_amdgcn_mfma_f32_16x16x32_bf16(al, bS[ki][0], accS[mt], 0, 0, 0);
                accS[mt] = __builtin_amdgcn_mfma_f32_16x16x32_bf16(ah, bS[ki][1], accS[mt], 0, 0, 0);
                accG[mt] = __builtin_amdgcn_mfma_f32_16x16x32_bf16(ah, bG[ki][0], accG[mt], 0, 0, 0);
                accG[mt] = __builtin_amdgcn_mfma_f32_16x16x32_bf16(al, bG[ki][0], accG[mt], 0, 0, 0);
                accG[mt] = __builtin_amdgcn_mfma_f32_16x16x32_bf16(ah, bG[ki][1], accG[mt], 0, 0, 0);
            }
        }
        // linear coalesced nontemporal store (row = sorted pos within tile)
        const size_t p0 = (size_t)tile * 64;
#pragma unroll
        for (int mt = 0; mt < 4; ++mt) {
#pragma unroll
            for (int reg = 0; reg < 4; ++reg) {
                int row = mt * 16 + (lane >> 4) * 4 + reg;
                unsigned val = pack_bf2(accS[mt][reg], accG[mt][reg]);
                __builtin_nontemporal_store(val,
                    &C32[(p0 + row) * 128 + w * 16 + (lane & 15)]);
            }
        }
    }
}

// ===== sorted apply (r4 v2) =====
__global__ void __launch_bounds__(256) edge_apply_sorted(
    const u32x2* __restrict__ C64, const u32x2* __restrict__ PQ64,
    const int* __restrict__ ssrc, const int* __restrict__ sdst,
    const float* __restrict__ bs, const float* __restrict__ bg,
    float* __restrict__ acc)
{
    __shared__ int s_src[4][64];
    __shared__ int s_dst[4][64];
    const int t = threadIdx.x & 63;
    const int w = threadIdx.x >> 6;
    const size_t p0 = ((size_t)blockIdx.x * 4 + w) * 64;
    s_src[w][t] = ssrc[p0 + t];
    s_dst[w][t] = sdst[p0 + t];
    __syncthreads();

    const float2 bsv = *(const float2*)&bs[2 * t];
    const float2 bgv = *(const float2*)&bg[2 * t];

    int cur = s_src[w][0];
    u32x2 pv = PQ64[(size_t)cur * 128 + t];
    float psA = unp_lo(pv.x) + bsv.x, pgA = unp_hi(pv.x) + bgv.x;
    float psB = unp_lo(pv.y) + bsv.y, pgB = unp_hi(pv.y) + bgv.y;

    u32x2 c0 = __builtin_nontemporal_load(&C64[(p0 + 0) * 64 + t]);
    u32x2 c1 = __builtin_nontemporal_load(&C64[(p0 + 1) * 64 + t]);
    u32x2 c2 = __builtin_nontemporal_load(&C64[(p0 + 2) * 64 + t]);
    u32x2 c3 = __builtin_nontemporal_load(&C64[(p0 + 3) * 64 + t]);
    u32x2 q0 = PQ64[(size_t)s_dst[w][0] * 128 + 64 + t];
    u32x2 q1 = PQ64[(size_t)s_dst[w][1] * 128 + 64 + t];
    u32x2 q2 = PQ64[(size_t)s_dst[w][2] * 128 + 64 + t];
    u32x2 q3 = PQ64[(size_t)s_dst[w][3] * 128 + 64 + t];
    u32x2 r0 = pv, r1 = pv, r2 = pv, r3 = pv;
    if (s_src[w][1] != s_src[w][0]) r1 = PQ64[(size_t)s_src[w][1] * 128 + t];
    if (s_src[w][2] != s_src[w][1]) r2 = PQ64[(size_t)s_src[w][2] * 128 + t];
    if (s_src[w][3] != s_src[w][2]) r3 = PQ64[(size_t)s_src[w][3] * 128 + t];
    float accA = 0.f, accB = 0.f;

#define PROC_CORE(i, cc, qq, rr)                                           \
    {                                                                      \
        int src_ = s_src[w][(i)];                                          \
        if (src_ != cur) {                                                 \
            atomicAdd(&acc[(size_t)cur * AD + 2 * t],     accA);           \
            atomicAdd(&acc[(size_t)cur * AD + 2 * t + 1], accB);           \
            accA = 0.f; accB = 0.f; cur = src_;                            \
            psA = unp_lo(rr.x) + bsv.x; pgA = unp_hi(rr.x) + bgv.x;        \
            psB = unp_lo(rr.y) + bsv.y; pgB = unp_hi(rr.y) + bgv.y;        \
        }                                                                  \
        float sA = unp_lo(cc.x) + unp_lo(qq.x) + psA;                      \
        float gA = unp_hi(cc.x) + unp_hi(qq.x) + pgA;                      \
        float sB = unp_lo(cc.y) + unp_lo(qq.y) + psB;                      \
        float gB = unp_hi(cc.y) + unp_hi(qq.y) + pgB;                      \
        accA += msg_f(sA, gA);                                             \
        accB += msg_f(sB, gB);                                             \
    }

#define PROC(i, cc, qq, rr)                                                \
    PROC_CORE(i, cc, qq, rr)                                               \
    {                                                                      \
        int nx_ = (i) + 4;                                                 \
        cc = __builtin_nontemporal_load(&C64[(p0 + nx_) * 64 + t]);        \
        qq = PQ64[(size_t)s_dst[w][nx_] * 128 + 64 + t];                   \
        if (s_src[w][nx_] != s_src[w][nx_ - 1])                            \
            rr = PQ64[(size_t)s_src[w][nx_] * 128 + t];                    \
    }

    for (int j = 0; j < 15; ++j) {
        int b = 4 * j;
        PROC(b + 0, c0, q0, r0)
        PROC(b + 1, c1, q1, r1)
        PROC(b + 2, c2, q2, r2)
        PROC(b + 3, c3, q3, r3)
    }
    PROC_CORE(60, c0, q0, r0)
    PROC_CORE(61, c1, q1, r1)
    PROC_CORE(62, c2, q2, r2)
    PROC_CORE(63, c3, q3, r3)

    atomicAdd(&acc[(size_t)cur * AD + 2 * t],     accA);
    atomicAdd(&acc[(size_t)cur * AD + 2 * t + 1], accB);
#undef PROC
#undef PROC_CORE
}

// ===== final softplus =====
__global__ void __launch_bounds__(256) act_k(float* __restrict__ acc)
{
    size_t i = ((size_t)blockIdx.x * 256 + threadIdx.x) * 4;
    float4 v = *(float4*)&acc[i];
    v.x = softplus_f(v.x);
    v.y = softplus_f(v.y);
    v.z = softplus_f(v.z);
    v.w = softplus_f(v.w);
    *(float4*)&acc[i] = v;
}

// ===== Tier B fallback (round-1, known good) =====
__global__ void __launch_bounds__(128) node_mm_f32(
    const float* __restrict__ x, const float* __restrict__ Ks,
    const float* __restrict__ Kg, float* __restrict__ PQ)
{
    __shared__ float xs[8][AD];
    const int t = threadIdx.x;
    const int row0 = blockIdx.x * 8;
#pragma unroll
    for (int r = 0; r < 8; ++r) xs[r][t] = x[(size_t)(row0 + r) * AD + t];
    __syncthreads();
    float aPs[8] = {}, aQs[8] = {}, aPg[8] = {}, aQg[8] = {};
    for (int k = 0; k < AD; ++k) {
        float ks_s = Ks[k * AD + t];
        float ks_d = Ks[(AD + k) * AD + t];
        float kg_s = Kg[k * AD + t];
        float kg_d = Kg[(AD + k) * AD + t];
#pragma unroll
        for (int r = 0; r < 8; ++r) {
            float xv = xs[r][k];
            aPs[r] = fmaf(xv, ks_s, aPs[r]);
            aQs[r] = fmaf(xv, ks_d, aQs[r]);
            aPg[r] = fmaf(xv, kg_s, aPg[r]);
            aQg[r] = fmaf(xv, kg_d, aQg[r]);
        }
    }
#pragma unroll
    for (int r = 0; r < 8; ++r) {
        float* o = PQ + (size_t)(row0 + r) * 512;
        *(float2*)&o[2 * t]       = make_float2(aPs[r], aPg[r]);
        *(float2*)&o[256 + 2 * t] = make_float2(aQs[r], aQg[r]);
    }
}

__global__ void __launch_bounds__(256) edge_fused(
    const float* __restrict__ ef, const float* __restrict__ Ks,
    const float* __restrict__ Kg, const float* __restrict__ PQ,
    const int* __restrict__ pidx, const float* __restrict__ bs,
    const float* __restrict__ bg, float* __restrict__ acc)
{
    __shared__ float KB[ED][2 * AD];
    __shared__ float es[64][ED];
    const int t = threadIdx.x;
    for (int i = t; i < ED * AD; i += 256) {
        int k = i >> 7, n = i & 127;
        KB[k][2 * n]     = Ks[(2 * AD + k) * AD + n];
        KB[k][2 * n + 1] = Kg[(2 * AD + k) * AD + n];
    }
    const size_t e0 = (size_t)blockIdx.x * 64;
    for (int i = t; i < 64 * ED; i += 256) ((float*)es)[i] = ef[e0 * ED + i];
    __syncthreads();
    const int le = t >> 7, n = t & 127;
    const float bsn = bs[n], bgn = bg[n];
    for (int base = le * 8; base < 64; base += 16) {
        float accS[8] = {}, accG[8] = {};
        for (int k4 = 0; k4 < ED / 4; ++k4) {
            float2 kv0 = *(const float2*)&KB[4 * k4 + 0][2 * n];
            float2 kv1 = *(const float2*)&KB[4 * k4 + 1][2 * n];
            float2 kv2 = *(const float2*)&KB[4 * k4 + 2][2 * n];
            float2 kv3 = *(const float2*)&KB[4 * k4 + 3][2 * n];
#pragma unroll
            for (int r = 0; r < 8; ++r) {
                float4 ev = *(const float4*)&es[base + r][4 * k4];
                accS[r] = fmaf(ev.x, kv0.x, accS[r]);
                accG[r] = fmaf(ev.x, kv0.y, accG[r]);
                accS[r] = fmaf(ev.y, kv1.x, accS[r]);
                accG[r] = fmaf(ev.y, kv1.y, accG[r]);
                accS[r] = fmaf(ev.z, kv2.x, accS[r]);
                accG[r] = fmaf(ev.z, kv2.y, accG[r]);
                accS[r] = fmaf(ev.w, kv3.x, accS[r]);
                accG[r] = fmaf(ev.w, kv3.y, accG[r]);
            }
        }
#pragma unroll
        for (int r = 0; r < 8; ++r) {
            size_t e = e0 + base + r;
            int src = pidx[2 * e], dst = pidx[2 * e + 1];
            float2 pv = *(const float2*)&PQ[(size_t)src * 512 + 2 * n];
            float2 qv = *(const float2*)&PQ[(size_t)dst * 512 + 256 + 2 * n];
            float s = accS[r] + pv.x + qv.x + bsn;
            float g = accG[r] + pv.y + qv.y + bgn;
            atomicAdd(&acc[(size_t)src * AD + n], sigmoid_fast(s) * softplus_f(g));
        }
    }
}

// ===== launch =====
extern "C" void kernel_launch(void* const* d_in, const int* in_sizes, int n_in,
                              void* d_out, int out_size, void* d_ws, size_t ws_size,
                              hipStream_t stream)
{
    const float* atom = (const float*)d_in[0];
    const float* ef   = (const float*)d_in[1];
    const float* Ks   = (const float*)d_in[3];
    const float* bs   = (const float*)d_in[4];
    const float* Kg   = (const float*)d_in[5];
    const float* bg   = (const float*)d_in[6];
    const int*   pidx = (const int*)d_in[7];

    float* acc = (float*)d_out;

    char* w = (char*)d_ws;
    const size_t PQ_B   = (size_t)NN * 256 * 4;   //  51.2 MB
    const size_t C_B    = (size_t)NE * 128 * 4;   // 409.6 MB
    const size_t CNT_B  = (size_t)NN * 4;
    const size_t IDX_B  = (size_t)NE * 4;
    const size_t PART_B = 256 * 4;
    unsigned* PQ32 = (unsigned*)w;  w += PQ_B;
    unsigned* C32  = (unsigned*)w;  w += C_B;
    unsigned* cnt  = (unsigned*)w;  w += CNT_B;
    unsigned* curp = (unsigned*)w;  w += CNT_B;
    int*      sid  = (int*)w;       w += IDX_B;
    int*      ssrc = (int*)w;       w += IDX_B;
    int*      sdst = (int*)w;       w += IDX_B;
    unsigned* part = (unsigned*)w;  w += PART_B;
    const size_t TOTAL_A = PQ_B + C_B + 2 * CNT_B + 3 * IDX_B + PART_B;

    if (ws_size >= TOTAL_A) {
        hipMemsetAsync(cnt, 0, CNT_B, stream);
        hist_k<<<NE / 256, 256, 0, stream>>>(pidx, cnt);
        scan1_k<<<NSCAN, 256, 0, stream>>>(cnt, curp, part);
        scan2_k<<<1, 256, 0, stream>>>(part);
        scan3_k<<<NSCAN, 256, 0, stream>>>(curp, part);
        scatter_k<<<NE / 256, 256, 0, stream>>>(pidx, curp, sid, ssrc, sdst);
        edge_c_mfma<<<512, 512, 0, stream>>>(ef, Ks, Kg, sid, C32);

        for (int s = 0; s < NSTEPS; ++s) {
            node_mm_b16<<<NN / 16, 128, 0, stream>>>(atom, acc, Ks, Kg, PQ32,
                                                     s == 0 ? 0 : 1);
            edge_apply_sorted<<<NE / 256, 256, 0, stream>>>(
                (const u32x2*)C32, (const u32x2*)PQ32, ssrc, sdst, bs, bg, acc);
        }
        act_k<<<(NN * AD) / 1024, 256, 0, stream>>>(acc);
    } else {
        float* PQ = (float*)d_ws;
        hipMemcpyAsync(acc, atom, (size_t)NN * AD * sizeof(float),
                       hipMemcpyDeviceToDevice, stream);
        for (int s = 0; s < NSTEPS; ++s) {
            node_mm_f32<<<NN / 8, 128, 0, stream>>>(acc, Ks, Kg, PQ);
            edge_fused<<<NE / 64, 256, 0, stream>>>(ef, Ks, Kg, PQ, pidx, bs, bg, acc);
            act_k<<<(NN * AD) / 1024, 256, 0, stream>>>(acc);
        }
    }
}